// Round 9
// baseline (314.591 us; speedup 1.0000x reference)
//
#include <hip/hip_runtime.h>
#include <hip/hip_bf16.h>

// ViT attention, B=4 S=2048 C=1024 H=16 D=64. fp32 I/O, bf16/f16 MFMA inside.
// cast -> rope_table -> qkv_gemm(+bias+rope+scale) -> vtrans -> attn -> proj.
// R1: PV 16x16x32_f16 via permlane lq-transpose.  R3: ssum ones-MFMA +
//     zero-C + XCD remap (attn) + s_nop hazard fix.  R4/R5/R6: GEMM schedule
//     reworks all neutral (MfmaUtil pinned ~24% -> not schedule-local).
// R7: XCD locality remap for GEMMs: +4%, FETCH unchanged.
// R8: non-temporal stores on write-once streams -> compile error (builtin
//     rejects HIP_vector_type).
// R9: R8 retry with ext_vector_type pointers (u16x4/u32x4/f32x4) for all
//     NT accesses. Theory unchanged: stop 48MB+ write streams from evicting
//     A/B panels from the 4MB/XCD L2. Decisive: qkv FETCH 90MB -> ~35MB.

typedef unsigned short u16;
using bf16x8 = __attribute__((ext_vector_type(8))) __bf16;
using f32x4  = __attribute__((ext_vector_type(4))) float;
using f16x8  = __attribute__((ext_vector_type(8))) _Float16;
using fp16v2 = __attribute__((ext_vector_type(2))) __fp16;   // cvt_pkrtz native
using u16x4  = __attribute__((ext_vector_type(4))) unsigned short;
using u32x4  = __attribute__((ext_vector_type(4))) unsigned int;

#define LDT 80  // vtrans LDS pad only

__device__ __forceinline__ u16 f2bf(float f) {
  union { float f; unsigned u; } un; un.f = f;
  unsigned r = un.u + 0x7FFFu + ((un.u >> 16) & 1u);  // RNE
  return (u16)(r >> 16);
}
__device__ __forceinline__ float bf2f(u16 b) {
  union { unsigned u; float f; } un; un.u = ((unsigned)b) << 16;
  return un.f;
}

// non-temporal helpers (gfx950 'nt' -> bypass L2 allocation)
__device__ __forceinline__ void nts_u16(u16* p, u16 v) {
  __builtin_nontemporal_store(v, p);
}
__device__ __forceinline__ void nts_f32(float* p, float v) {
  __builtin_nontemporal_store(v, p);
}
__device__ __forceinline__ void nts_u16x4(void* p, u16x4 v) {
  __builtin_nontemporal_store(v, (u16x4*)p);
}
__device__ __forceinline__ u32x4 ntl_u32x4(const void* p) {
  return __builtin_nontemporal_load((const u32x4*)p);
}
__device__ __forceinline__ f32x4 ntl_f32x4(const void* p) {
  return __builtin_nontemporal_load((const f32x4*)p);
}

// pack two f32 -> two f16 (RTZ) into one dword
__device__ __forceinline__ unsigned pkrtz_u32(float a, float b) {
  union { fp16v2 v; unsigned u; } un;
  un.v = __builtin_amdgcn_cvt_pkrtz(a, b);
  return un.u;
}

// x' = [x.lo32, y.lo32]; y' = [x.hi32, y.hi32]  (gather 32-lane halves)
__device__ __forceinline__ void pswap32(unsigned &x, unsigned &y) {
  asm volatile("v_permlane32_swap_b32 %0, %1" : "+v"(x), "+v"(y));
}
// rows of 16 lanes: x' = [x0,y0,x2,y2]; y' = [x1,y1,x3,y3]
// s_nop 1 embedded: final writers of pa regs; hazard recognizer cannot see
// VALU-write->MFMA-read wait states for INLINEASM producers (R2 NaN cause).
__device__ __forceinline__ void pswap16(unsigned &x, unsigned &y) {
  asm volatile("v_permlane16_swap_b32 %0, %1\n\ts_nop 1" : "+v"(x), "+v"(y));
}

// async 16B/lane global -> LDS (lands at ldsbase + lane*16)
__device__ __forceinline__ void glds16(const void* g, void* l) {
  __builtin_amdgcn_global_load_lds(
      (__attribute__((address_space(1))) void*)(g),
      (__attribute__((address_space(3))) void*)(l), 16, 0, 0);
}

// ---------------- fp32 -> bf16 cast (vectorized x4) ------------------------
__global__ __launch_bounds__(256) void f2bf_kernel(
    const float* __restrict__ src, u16* __restrict__ dst, int n4)
{
  int i = blockIdx.x * 256 + threadIdx.x;
  if (i < n4) {
    f32x4 v = ntl_f32x4((const f32x4*)src + i);
    u16x4 o;
    o[0] = f2bf(v[0]); o[1] = f2bf(v[1]); o[2] = f2bf(v[2]); o[3] = f2bf(v[3]);
    nts_u16x4((u16x4*)dst + i, o);
  }
}

// ------- RoPE table: RT[m][lr] = {cos[m][lr+16j]}{sin[m][lr+16j]} bf16 -----
__global__ __launch_bounds__(256) void rope_table_kernel(
    const float* __restrict__ cs, const float* __restrict__ sn,
    u16* __restrict__ RT)
{
  int t = blockIdx.x * 256 + threadIdx.x;   // 8192*16 = 131072 exact
  int lr = t & 15, m = t >> 4;
  const float* c = cs + (size_t)m * 64;
  const float* s = sn + (size_t)m * 64;
  alignas(16) u16 o[8];
  o[0] = f2bf(c[lr]); o[1] = f2bf(c[lr + 16]);
  o[2] = f2bf(c[lr + 32]); o[3] = f2bf(c[lr + 48]);
  o[4] = f2bf(s[lr]); o[5] = f2bf(s[lr + 16]);
  o[6] = f2bf(s[lr + 32]); o[7] = f2bf(s[lr + 48]);
  *(uint4*)(RT + (size_t)t * 8) = *(const uint4*)o;   // RT stays cacheable
}

// ------ 128x128 BT-GEMM core, counted-vmcnt dbuf + XOR bank swizzle --------
__device__ __forceinline__ void gemm_stage_128(
    const u16* __restrict__ A, const u16* __restrict__ Bm, int K,
    int row0, int col0, int k0, u16* AsB, u16* BsB,
    int w, int lrow, int lcol8)
{
#pragma unroll
  for (int p = 0; p < 4; ++p) {
    int base = w * 32 + p * 8;
    int rr = base + lrow;
    int cc = (lcol8 ^ (rr & 7)) << 3;
    glds16(A  + (size_t)(row0 + rr) * K + k0 + cc, AsB + base * 64);
    glds16(Bm + (size_t)(col0 + rr) * K + k0 + cc, BsB + base * 64);
  }
}

__device__ __forceinline__ void gemm_compute_128(
    const u16* __restrict__ Asc, const u16* __restrict__ Bsc,
    int wm, int wn, int lr, int lq, f32x4 acc[4][4])
{
#pragma unroll
  for (int kx = 0; kx < 2; ++kx) {
    bf16x8 af[4], bv[4];
    const int sl = (((kx << 2) + lq) ^ (lr & 7)) << 3;
#pragma unroll
    for (int i = 0; i < 4; ++i) {
      af[i] = *(const bf16x8*)(&Asc[(wm + i * 16 + lr) * 64 + sl]);
      bv[i] = *(const bf16x8*)(&Bsc[(wn + i * 16 + lr) * 64 + sl]);
    }
#pragma unroll
    for (int i = 0; i < 4; ++i)
#pragma unroll
      for (int j = 0; j < 4; ++j)
        acc[i][j] = __builtin_amdgcn_mfma_f32_16x16x32_bf16(af[i], bv[j], acc[i][j], 0, 0, 0);
  }
}

// Counted-vmcnt double-buffered K-loop (R5, perf-equal to all variants).
__device__ __forceinline__ void gemm_core_128(
    const u16* __restrict__ A, const u16* __restrict__ Bm, int K,
    int row0, int col0, u16 (*As)[128 * 64], u16 (*Bs)[128 * 64],
    f32x4 acc[4][4])
{
  const int tid = threadIdx.x;
  const int lane = tid & 63;
  const int w  = tid >> 6;
  const int wm = (w >> 1) << 6;
  const int wn = (w & 1) << 6;
  const int lr = lane & 15;
  const int lq = lane >> 4;
  const int lrow = lane >> 3;
  const int lcol8 = lane & 7;
  const int nk = K >> 6;

  gemm_stage_128(A, Bm, K, row0, col0, 0, As[0], Bs[0], w, lrow, lcol8);

  for (int ks = 0; ks < nk - 1; ++ks) {
    const int cur = ks & 1;
    gemm_stage_128(A, Bm, K, row0, col0, (ks + 1) << 6,
                   As[cur ^ 1], Bs[cur ^ 1], w, lrow, lcol8);
    asm volatile("s_waitcnt vmcnt(8)" ::: "memory");  // 8 newest may fly on
    __builtin_amdgcn_s_barrier();
    __builtin_amdgcn_sched_barrier(0);   // no ds_read hoists above barrier
    gemm_compute_128(As[cur], Bs[cur], wm, wn, lr, lq, acc);
    __builtin_amdgcn_sched_barrier(0);   // no compute sinks below barrier
    __builtin_amdgcn_s_barrier();
  }
  asm volatile("s_waitcnt vmcnt(0)" ::: "memory");    // last tile: full drain
  __builtin_amdgcn_s_barrier();
  __builtin_amdgcn_sched_barrier(0);
  gemm_compute_128(As[(nk - 1) & 1], Bs[(nk - 1) & 1], wm, wn, lr, lq, acc);
}

// ------- QKV projection + bias + fused RoPE (table) + scale ----------------
__global__ __launch_bounds__(256) void qkv_gemm_kernel(
    const u16* __restrict__ hs, const u16* __restrict__ wq,
    const float* __restrict__ bias, const u16* __restrict__ RT,
    u16* __restrict__ Q, u16* __restrict__ K, u16* __restrict__ V)
{
  __shared__ __align__(16) u16 As[2][128 * 64];
  __shared__ __align__(16) u16 Bs[2][128 * 64];
  f32x4 acc[4][4];
#pragma unroll
  for (int i = 0; i < 4; ++i)
#pragma unroll
    for (int j = 0; j < 4; ++j) acc[i][j] = (f32x4){0.f, 0.f, 0.f, 0.f};

  // XCD locality remap (R7): each XCD runs complete row-panel runs.
  const int flat = blockIdx.x + blockIdx.y * 24;   // 0..1535, x fastest
  const int xcd = flat & 7, j = flat >> 3;         // j in 0..191
  const int row0 = (xcd + ((j / 24) << 3)) << 7;   // m-panel = xcd + 8*(j/24)
  const int col0 = (j % 24) << 7;                  // n in [0,3072)
  gemm_core_128(hs, wq, 1024, row0, col0, As, Bs, acc);

  const int lane = threadIdx.x & 63;
  const int w = threadIdx.x >> 6;
  const int lr = lane & 15, lq = lane >> 4;
  const int wm = (w >> 1) << 6, wn = (w & 1) << 6;
  const int ncol = col0 + wn;          // 64-aligned -> single (wh,h)
  const int wh = ncol >> 10;           // 0=q 1=k 2=v (wave-uniform)
  const int h  = (ncol & 1023) >> 6;
  u16* dst = (wh == 0) ? Q : ((wh == 1) ? K : V);
  const float b0 = bias[ncol + lr];
  const float b1 = bias[ncol + 16 + lr];
  const float b2 = bias[ncol + 32 + lr];
  const float b3 = bias[ncol + 48 + lr];

#pragma unroll
  for (int i = 0; i < 4; ++i)
#pragma unroll
    for (int r = 0; r < 4; ++r) {
      int m = row0 + wm + i * 16 + lq * 4 + r;   // = b*2048 + s
      float v0 = acc[i][0][r] + b0;
      float v1 = acc[i][1][r] + b1;
      float v2 = acc[i][2][r] + b2;
      float v3 = acc[i][3][r] + b3;
      int b = m >> 11, s = m & 2047;
      size_t off = ((size_t)((b << 4) + h) * 2048 + s) * 64;
      if (wh == 2) {                   // V -> f16 (NT: read much later)
        union { _Float16 h2; u16 u; } c0, c1, c2, c3;
        c0.h2 = (_Float16)v0; c1.h2 = (_Float16)v1;
        c2.h2 = (_Float16)v2; c3.h2 = (_Float16)v3;
        nts_u16(dst + off + lr,      c0.u);
        nts_u16(dst + off + 16 + lr, c1.u);
        nts_u16(dst + off + 32 + lr, c2.u);
        nts_u16(dst + off + 48 + lr, c3.u);
      } else {                         // RoPE via table; Q gets 1/8*log2(e)
        alignas(16) u16 rv[8];
        *(uint4*)rv = *(const uint4*)(RT + ((size_t)m * 16 + lr) * 8);
        float o0 = v0 * bf2f(rv[0]) - v2 * bf2f(rv[4]);
        float o1 = v1 * bf2f(rv[1]) - v3 * bf2f(rv[5]);
        float o2 = v2 * bf2f(rv[2]) + v0 * bf2f(rv[6]);
        float o3 = v3 * bf2f(rv[3]) + v1 * bf2f(rv[7]);
        float sc8 = (wh == 0) ? 0.1803368801f : 1.0f;
        nts_u16(dst + off + lr,      f2bf(o0 * sc8));
        nts_u16(dst + off + 16 + lr, f2bf(o1 * sc8));
        nts_u16(dst + off + 32 + lr, f2bf(o2 * sc8));
        nts_u16(dst + off + 48 + lr, f2bf(o3 * sc8));
      }
    }
}

// ---------------- V [B,H,S,D] -> Vt [B,H,D,S] (bit-moves) ------------------
__global__ __launch_bounds__(256) void vtrans_kernel(
    const u16* __restrict__ V, u16* __restrict__ Vt)
{
  __shared__ __align__(16) u16 T[64][LDT];
  const int bh = blockIdx.y;
  const int s0 = blockIdx.x * 64;
  const u16* src = V + ((size_t)bh * 2048 + s0) * 64;
  const int r = threadIdx.x >> 2;
  const int c = (threadIdx.x & 3) << 4;
  *(u32x4*)(&T[r][c])     = ntl_u32x4(src + r * 64 + c);
  *(u32x4*)(&T[r][c + 8]) = ntl_u32x4(src + r * 64 + c + 8);
  __syncthreads();
  alignas(16) u16 tmp[16];
#pragma unroll
  for (int j = 0; j < 16; ++j) tmp[j] = T[c + j][r];
  u16* dst = Vt + ((size_t)bh * 64 + r) * 2048 + s0 + c;
  nts_u16x4(dst,      ((u16x4*)tmp)[0]);
  nts_u16x4(dst + 4,  ((u16x4*)tmp)[1]);
  nts_u16x4(dst + 8,  ((u16x4*)tmp)[2]);
  nts_u16x4(dst + 12, ((u16x4*)tmp)[3]);
}

// ---- attention: S^T trick, double-buffered staging, 1 barrier/iter --------
__device__ __forceinline__ void attn_stage(
    const u16* __restrict__ Kh, const u16* __restrict__ Vh, int kv0,
    u16* KsB, u16* VsB, int w, int lrow, int lcol8)
{
#pragma unroll
  for (int p = 0; p < 2; ++p) {
    int base = w * 16 + p * 8;
    int rr = base + lrow;
    int cc = (lcol8 ^ (rr & 7)) << 3;
    glds16(Kh + (size_t)(kv0 + rr) * 64 + cc, KsB + base * 64);
    glds16(Vh + (size_t)rr * 2048 + kv0 + cc, VsB + base * 64);
  }
}

__global__ __launch_bounds__(256, 4) void attn_kernel(
    const u16* __restrict__ Q, const u16* __restrict__ K,
    const u16* __restrict__ Vt, u16* __restrict__ O)
{
  __shared__ __align__(16) u16 Ks[2][64 * 64];
  __shared__ __align__(16) u16 Vs[2][64 * 64];
  // XCD-clustering remap: all 16 q-blocks of one (b,h) land on one XCD.
  const int flat = blockIdx.x + (blockIdx.y << 4);   // 0..1023
  const int xcd = flat & 7, j = flat >> 3;           // j in 0..127
  const int bh = (xcd << 3) + (j & 7);               // bijective
  const int q0 = (j >> 3) << 7;
  const int b = bh >> 4, h = bh & 15;
  const u16* Qh = Q  + (size_t)bh * (2048 * 64);
  const u16* Kh = K  + (size_t)bh * (2048 * 64);
  const u16* Vh = Vt + (size_t)bh * (64 * 2048);
  const int tid = threadIdx.x, lane = tid & 63, w = tid >> 6;
  const int lr = lane & 15, lq = lane >> 4;
  const int lrow = lane >> 3, lcol8 = lane & 7;
  const int wq0 = w * 32;

  // prefetch tile 0
  attn_stage(Kh, Vh, 0, Ks[0], Vs[0], w, lrow, lcol8);

  // Q fragments: iter-invariant, straight from global (B-operand, n=q)
  bf16x8 qa[2][2];
#pragma unroll
  for (int mi = 0; mi < 2; ++mi)
#pragma unroll
    for (int kx = 0; kx < 2; ++kx)
      qa[mi][kx] = *(const bf16x8*)(Qh + (size_t)(q0 + wq0 + mi * 16 + lr) * 64 + kx * 32 + lq * 8);

  const f32x4 Z = (f32x4){0.f, 0.f, 0.f, 0.f};   // shared zero C-in
  const f16x8 ones = {(_Float16)1.f, (_Float16)1.f, (_Float16)1.f, (_Float16)1.f,
                      (_Float16)1.f, (_Float16)1.f, (_Float16)1.f, (_Float16)1.f};

  f32x4 acc_o[2][4];
  f32x4 ssum[2];                                  // P row-sums via MFMA
#pragma unroll
  for (int mi = 0; mi < 2; ++mi) {
    ssum[mi] = (f32x4){0.f, 0.f, 0.f, 0.f};
#pragma unroll
    for (int td = 0; td < 4; ++td) acc_o[mi][td] = (f32x4){0.f, 0.f, 0.f, 0.f};
  }

  for (int it = 0; it < 32; ++it) {
    const int cur = it & 1;
    __syncthreads();                       // drains staging of buf(cur)
    if (it + 1 < 32)                       // prefetch next into other buffer
      attn_stage(Kh, Vh, (it + 1) << 6, Ks[cur ^ 1], Vs[cur ^ 1], w, lrow, lcol8);
    const u16* Kc = Ks[cur];
    const u16* Vc = Vs[cur];

    // S^T = K Q^T : tiles [kv=tj*16][q=mi*16], contraction over d
    f32x4 st[4][2];
#pragma unroll
    for (int kx = 0; kx < 2; ++kx) {
      bf16x8 ka[4];
#pragma unroll
      for (int tj = 0; tj < 4; ++tj) {
        int row = tj * 16 + lr;
        ka[tj] = *(const bf16x8*)(&Kc[row * 64 + ((((kx << 2) + lq) ^ (lr & 7)) << 3)]);
      }
#pragma unroll
      for (int tj = 0; tj < 4; ++tj)
#pragma unroll
        for (int mi = 0; mi < 2; ++mi)
          st[tj][mi] = __builtin_amdgcn_mfma_f32_16x16x32_bf16(
              ka[tj], qa[mi][kx], kx ? st[tj][mi] : Z, 0, 0, 0);
    }

    // p = 2^s (log2e pre-folded into Q). Build K=32 f16 A-frags via
    // 2x permlane32_swap + 2x permlane16_swap lq-transpose.
    f16x8 pa[2][2];
#pragma unroll
    for (int mi = 0; mi < 2; ++mi)
#pragma unroll
      for (int t32 = 0; t32 < 2; ++t32) {
        unsigned dw[4];
#pragma unroll
        for (int tt = 0; tt < 2; ++tt) {
          const int tj = t32 * 2 + tt;
          float e0 = __builtin_amdgcn_exp2f(st[tj][mi][0]);
          float e1 = __builtin_amdgcn_exp2f(st[tj][mi][1]);
          float e2 = __builtin_amdgcn_exp2f(st[tj][mi][2]);
          float e3 = __builtin_amdgcn_exp2f(st[tj][mi][3]);
          dw[tt * 2 + 0] = pkrtz_u32(e0, e1);   // kv_local lq*4+{0,1}
          dw[tt * 2 + 1] = pkrtz_u32(e2, e3);   // kv_local lq*4+{2,3}
        }
        pswap32(dw[0], dw[2]);
        pswap32(dw[1], dw[3]);
        pswap16(dw[0], dw[2]);
        pswap16(dw[1], dw[3]);
        union { unsigned u[4]; f16x8 v; } P;
        P.u[0] = dw[0]; P.u[1] = dw[1]; P.u[2] = dw[2]; P.u[3] = dw[3];
        pa[mi][t32] = P.v;
      }

    // O += P V; row-sums ride the matrix pipe after the PV MFMAs.
#pragma unroll
    for (int t32 = 0; t32 < 2; ++t32) {
      f16x8 bv[4];
#pragma unroll
      for (int td = 0; td < 4; ++td) {
        int row = td * 16 + lr;
        bv[td] = *(const f16x8*)(&Vc[row * 64 + ((((t32 << 2) + lq) ^ (lr & 7)) << 3)]);
      }
#pragma unroll
      for (int td = 0; td < 4; ++td)
#pragma unroll
        for (int mi = 0; mi < 2; ++mi)
          acc_o[mi][td] = __builtin_amdgcn_mfma_f32_16x16x32_f16(pa[mi][t32], bv[td], acc_o[mi][td], 0, 0, 0);
#pragma unroll
      for (int mi = 0; mi < 2; ++mi)
        ssum[mi] = __builtin_amdgcn_mfma_f32_16x16x32_f16(pa[mi][t32], ones, ssum[mi], 0, 0, 0);
    }
  }

  // ssum[mi][r] holds the denom for q-row lq*4+r (all lr identical)
#pragma unroll
  for (int mi = 0; mi < 2; ++mi)
#pragma unroll
    for (int r = 0; r < 4; ++r) {
      float inv = 1.f / ssum[mi][r];
      int qq = q0 + wq0 + mi * 16 + lq * 4 + r;
#pragma unroll
      for (int td = 0; td < 4; ++td) {
        int d = td * 16 + lr;
        nts_u16(O + (size_t)(b * 2048 + qq) * 1024 + h * 64 + d,
                f2bf(acc_o[mi][td][r] * inv));
      }
    }
}

// ---------------- output projection (fp32 out) -----------------------------
__global__ __launch_bounds__(256) void proj_gemm_kernel(
    const u16* __restrict__ X, const u16* __restrict__ wp,
    const float* __restrict__ bias, float* __restrict__ out)
{
  __shared__ __align__(16) u16 As[2][128 * 64];
  __shared__ __align__(16) u16 Bs[2][128 * 64];
  f32x4 acc[4][4];
#pragma unroll
  for (int i = 0; i < 4; ++i)
#pragma unroll
    for (int j = 0; j < 4; ++j) acc[i][j] = (f32x4){0.f, 0.f, 0.f, 0.f};

  // Same XCD locality remap (8 col-blocks per row-panel here).
  const int flat = blockIdx.x + (blockIdx.y << 3);   // 0..511, x fastest
  const int xcd = flat & 7, j = flat >> 3;           // j in 0..63
  const int row0 = (xcd + (j & ~7)) << 7;            // m-panel = xcd + 8*(j/8)
  const int col0 = (j & 7) << 7;
  gemm_core_128(X, wp, 1024, row0, col0, As, Bs, acc);

  const int lane = threadIdx.x & 63;
  const int w = threadIdx.x >> 6;
  const int wm = (w >> 1) << 6, wn = (w & 1) << 6;
#pragma unroll
  for (int i = 0; i < 4; ++i)
#pragma unroll
    for (int j2 = 0; j2 < 4; ++j2)
#pragma unroll
      for (int r = 0; r < 4; ++r) {
        int m = row0 + wm + i * 16 + ((lane >> 4) << 2) + r;
        int n = col0 + wn + j2 * 16 + (lane & 15);
        nts_f32(out + (size_t)m * 1024 + n, acc[i][j2][r] + bias[n]);
      }
}

extern "C" void kernel_launch(void* const* d_in, const int* in_sizes, int n_in,
                              void* d_out, int out_size, void* d_ws, size_t ws_size,
                              hipStream_t stream)
{
  const float* hs   = (const float*)d_in[0];
  const float* cs   = (const float*)d_in[1];
  const float* sn   = (const float*)d_in[2];
  const float* qkvw = (const float*)d_in[3];
  const float* qkvb = (const float*)d_in[4];
  const float* pw   = (const float*)d_in[5];
  const float* pb   = (const float*)d_in[6];
  float* out = (float*)d_out;

  const size_t NQ = (size_t)8192 * 1024;
  u16* hsb   = (u16*)d_ws;
  u16* qkvwb = hsb + NQ;
  u16* pwb   = qkvwb + 3145728;
  u16* Qb    = pwb + 1048576;
  u16* Kb    = Qb + NQ;
  u16* Vb    = Kb + NQ;      // f16
  u16* Vtb   = Vb + NQ;      // f16
  u16* RT    = Vtb + NQ;     // rope table, 8192*16*8 u16 = 2 MB
  u16* Ob    = hsb;          // alias: hs consumed after qkv

  f2bf_kernel<<<8192, 256, 0, stream>>>(hs, hsb, (int)(NQ / 4));
  f2bf_kernel<<<3072, 256, 0, stream>>>(qkvw, qkvwb, 3145728 / 4);
  f2bf_kernel<<<1024, 256, 0, stream>>>(pw, pwb, 1048576 / 4);
  rope_table_kernel<<<512, 256, 0, stream>>>(cs, sn, RT);

  qkv_gemm_kernel<<<dim3(24, 64), 256, 0, stream>>>(hsb, qkvwb, qkvb, RT, Qb, Kb, Vb);
  vtrans_kernel<<<dim3(32, 64), 256, 0, stream>>>(Vb, Vtb);
  attn_kernel<<<dim3(16, 64), 256, 0, stream>>>(Qb, Kb, Vtb, Ob);
  proj_gemm_kernel<<<dim3(8, 64), 256, 0, stream>>>(Ob, pwb, pb, out);
}

// Round 10
// 298.216 us; speedup vs baseline: 1.0549x; 1.0549x over previous
//
#include <hip/hip_runtime.h>
#include <hip/hip_bf16.h>

// ViT attention, B=4 S=2048 C=1024 H=16 D=64. fp32 I/O, bf16/f16 MFMA inside.
// prep(cast+rope) -> qkv_gemm(+bias+rope+scale) -> vtrans -> attn -> proj.
// R1: PV 16x16x32_f16 via permlane lq-transpose.  R3: ssum ones-MFMA +
//     zero-C + XCD remap (attn) + s_nop hazard fix.  R4/R5/R6: GEMM schedule
//     reworks all neutral.  R7: XCD locality remap for GEMMs (+4%).
// R8/R9: NT stores -> FETCH unchanged AND slower; eviction theory dead.
//     Reverted.
// R10: occupancy attack: BK=32 dbuf GEMM core (32KB LDS -> 5 blocks/CU vs 2)
//      with 64B-row swizzle (2-way = free); counted vmcnt(4). Latency-bound
//      K-loop hidden by TLP, not scheduling. + prep fusion (4 launches -> 1).

typedef unsigned short u16;
using bf16x8 = __attribute__((ext_vector_type(8))) __bf16;
using f32x4  = __attribute__((ext_vector_type(4))) float;
using f16x8  = __attribute__((ext_vector_type(8))) _Float16;
using fp16v2 = __attribute__((ext_vector_type(2))) __fp16;   // cvt_pkrtz native

#define LDT 80  // vtrans LDS pad only

__device__ __forceinline__ u16 f2bf(float f) {
  union { float f; unsigned u; } un; un.f = f;
  unsigned r = un.u + 0x7FFFu + ((un.u >> 16) & 1u);  // RNE
  return (u16)(r >> 16);
}
__device__ __forceinline__ float bf2f(u16 b) {
  union { unsigned u; float f; } un; un.u = ((unsigned)b) << 16;
  return un.f;
}

// pack two f32 -> two f16 (RTZ) into one dword
__device__ __forceinline__ unsigned pkrtz_u32(float a, float b) {
  union { fp16v2 v; unsigned u; } un;
  un.v = __builtin_amdgcn_cvt_pkrtz(a, b);
  return un.u;
}

// x' = [x.lo32, y.lo32]; y' = [x.hi32, y.hi32]  (gather 32-lane halves)
__device__ __forceinline__ void pswap32(unsigned &x, unsigned &y) {
  asm volatile("v_permlane32_swap_b32 %0, %1" : "+v"(x), "+v"(y));
}
// rows of 16 lanes: x' = [x0,y0,x2,y2]; y' = [x1,y1,x3,y3]
// s_nop 1 embedded: final writers of pa regs; hazard recognizer cannot see
// VALU-write->MFMA-read wait states for INLINEASM producers (R2 NaN cause).
__device__ __forceinline__ void pswap16(unsigned &x, unsigned &y) {
  asm volatile("v_permlane16_swap_b32 %0, %1\n\ts_nop 1" : "+v"(x), "+v"(y));
}

// async 16B/lane global -> LDS (lands at ldsbase + lane*16)
__device__ __forceinline__ void glds16(const void* g, void* l) {
  __builtin_amdgcn_global_load_lds(
      (__attribute__((address_space(1))) void*)(g),
      (__attribute__((address_space(3))) void*)(l), 16, 0, 0);
}

// --------- fused prep: 3x fp32->bf16 cast + RoPE table (1 launch) ----------
// blocks [0,8192): hs cast; [8192,11264): qkvw; [11264,12288): pw;
// [12288,12800): rope table. All region sizes are exact multiples.
__global__ __launch_bounds__(256) void prep_kernel(
    const float* __restrict__ hs, const float* __restrict__ qkvw,
    const float* __restrict__ pw, const float* __restrict__ cs,
    const float* __restrict__ sn, u16* __restrict__ hsb,
    u16* __restrict__ qkvwb, u16* __restrict__ pwb, u16* __restrict__ RT)
{
  const int bid = blockIdx.x;
  if (bid < 12288) {                       // one of the three casts
    const float* src; u16* dst; int i;
    if (bid < 8192)       { src = hs;   dst = hsb;   i = bid * 256; }
    else if (bid < 11264) { src = qkvw; dst = qkvwb; i = (bid - 8192) * 256; }
    else                  { src = pw;   dst = pwb;   i = (bid - 11264) * 256; }
    i += threadIdx.x;
    float4 v = ((const float4*)src)[i];
    ushort4 o;
    o.x = f2bf(v.x); o.y = f2bf(v.y); o.z = f2bf(v.z); o.w = f2bf(v.w);
    ((ushort4*)dst)[i] = o;
  } else {                                 // rope table
    int t = (bid - 12288) * 256 + threadIdx.x;   // 131072 exact
    int lr = t & 15, m = t >> 4;
    const float* c = cs + (size_t)m * 64;
    const float* s = sn + (size_t)m * 64;
    alignas(16) u16 o[8];
    o[0] = f2bf(c[lr]); o[1] = f2bf(c[lr + 16]);
    o[2] = f2bf(c[lr + 32]); o[3] = f2bf(c[lr + 48]);
    o[4] = f2bf(s[lr]); o[5] = f2bf(s[lr + 16]);
    o[6] = f2bf(s[lr + 32]); o[7] = f2bf(s[lr + 48]);
    *(uint4*)(RT + (size_t)t * 8) = *(const uint4*)o;
  }
}

// ====== 128x128 BT-GEMM core, BK=32 dbuf (32KB LDS -> 5 blocks/CU) =========
// LDS rows are 32 u16 (64B). Stage: 1KB/glds-set = 16 rows; swizzle
// cc=(lcol4^((rr>>1)&3))<<3 pre-applied on the GLOBAL source (LDS linear).
// Read: sl=(lq^((lr>>1)&3))<<3 -> per 16-lane group each (row-parity, slot)
// pair has exactly 2 lanes = conflict-free (m136: 2-way is free).
__device__ __forceinline__ void gemm_stage_32(
    const u16* __restrict__ A, const u16* __restrict__ Bm, int K,
    int row0, int col0, int k0, u16* AsB, u16* BsB,
    int w, int lrow16, int lcol4)
{
#pragma unroll
  for (int p = 0; p < 2; ++p) {
    int base = w * 32 + p * 16;
    int rr = base + lrow16;
    int cc = (lcol4 ^ ((rr >> 1) & 3)) << 3;
    glds16(A  + (size_t)(row0 + rr) * K + k0 + cc, AsB + base * 32);
    glds16(Bm + (size_t)(col0 + rr) * K + k0 + cc, BsB + base * 32);
  }
}

__device__ __forceinline__ void gemm_compute_32(
    const u16* __restrict__ Asc, const u16* __restrict__ Bsc,
    int wm, int wn, int lr, int lq, f32x4 acc[4][4])
{
  bf16x8 af[4], bv[4];
  const int sl = (lq ^ ((lr >> 1) & 3)) << 3;
#pragma unroll
  for (int i = 0; i < 4; ++i) {
    af[i] = *(const bf16x8*)(&Asc[(wm + i * 16 + lr) * 32 + sl]);
    bv[i] = *(const bf16x8*)(&Bsc[(wn + i * 16 + lr) * 32 + sl]);
  }
#pragma unroll
  for (int i = 0; i < 4; ++i)
#pragma unroll
    for (int j = 0; j < 4; ++j)
      acc[i][j] = __builtin_amdgcn_mfma_f32_16x16x32_bf16(af[i], bv[j], acc[i][j], 0, 0, 0);
}

// Counted-vmcnt double-buffered K-loop, BK=32 (4 glds/thread/step).
__device__ __forceinline__ void gemm_core_32(
    const u16* __restrict__ A, const u16* __restrict__ Bm, int K,
    int row0, int col0, u16 (*As)[128 * 32], u16 (*Bs)[128 * 32],
    f32x4 acc[4][4])
{
  const int tid = threadIdx.x;
  const int lane = tid & 63;
  const int w  = tid >> 6;
  const int wm = (w >> 1) << 6;
  const int wn = (w & 1) << 6;
  const int lr = lane & 15;
  const int lq = lane >> 4;
  const int lrow16 = lane >> 2;
  const int lcol4  = lane & 3;
  const int nk = K >> 5;

  gemm_stage_32(A, Bm, K, row0, col0, 0, As[0], Bs[0], w, lrow16, lcol4);

  for (int ks = 0; ks < nk - 1; ++ks) {
    const int cur = ks & 1;
    gemm_stage_32(A, Bm, K, row0, col0, (ks + 1) << 5,
                  As[cur ^ 1], Bs[cur ^ 1], w, lrow16, lcol4);
    asm volatile("s_waitcnt vmcnt(4)" ::: "memory");  // 4 newest fly on
    __builtin_amdgcn_s_barrier();
    __builtin_amdgcn_sched_barrier(0);
    gemm_compute_32(As[cur], Bs[cur], wm, wn, lr, lq, acc);
    __builtin_amdgcn_sched_barrier(0);
    __builtin_amdgcn_s_barrier();
  }
  asm volatile("s_waitcnt vmcnt(0)" ::: "memory");    // last tile drain
  __builtin_amdgcn_s_barrier();
  __builtin_amdgcn_sched_barrier(0);
  gemm_compute_32(As[(nk - 1) & 1], Bs[(nk - 1) & 1], wm, wn, lr, lq, acc);
}

// ------- QKV projection + bias + fused RoPE (table) + scale ----------------
__global__ __launch_bounds__(256) void qkv_gemm_kernel(
    const u16* __restrict__ hs, const u16* __restrict__ wq,
    const float* __restrict__ bias, const u16* __restrict__ RT,
    u16* __restrict__ Q, u16* __restrict__ K, u16* __restrict__ V)
{
  __shared__ __align__(16) u16 As[2][128 * 32];   // 16KB
  __shared__ __align__(16) u16 Bs[2][128 * 32];   // 16KB
  f32x4 acc[4][4];
#pragma unroll
  for (int i = 0; i < 4; ++i)
#pragma unroll
    for (int j = 0; j < 4; ++j) acc[i][j] = (f32x4){0.f, 0.f, 0.f, 0.f};

  // XCD locality remap (R7): each XCD runs complete row-panel runs.
  const int flat = blockIdx.x + blockIdx.y * 24;   // 0..1535, x fastest
  const int xcd = flat & 7, j = flat >> 3;         // j in 0..191
  const int row0 = (xcd + ((j / 24) << 3)) << 7;   // m-panel = xcd + 8*(j/24)
  const int col0 = (j % 24) << 7;                  // n in [0,3072)
  gemm_core_32(hs, wq, 1024, row0, col0, As, Bs, acc);

  const int lane = threadIdx.x & 63;
  const int w = threadIdx.x >> 6;
  const int lr = lane & 15, lq = lane >> 4;
  const int wm = (w >> 1) << 6, wn = (w & 1) << 6;
  const int ncol = col0 + wn;          // 64-aligned -> single (wh,h)
  const int wh = ncol >> 10;           // 0=q 1=k 2=v (wave-uniform)
  const int h  = (ncol & 1023) >> 6;
  u16* dst = (wh == 0) ? Q : ((wh == 1) ? K : V);
  const float b0 = bias[ncol + lr];
  const float b1 = bias[ncol + 16 + lr];
  const float b2 = bias[ncol + 32 + lr];
  const float b3 = bias[ncol + 48 + lr];

#pragma unroll
  for (int i = 0; i < 4; ++i)
#pragma unroll
    for (int r = 0; r < 4; ++r) {
      int m = row0 + wm + i * 16 + lq * 4 + r;   // = b*2048 + s
      float v0 = acc[i][0][r] + b0;
      float v1 = acc[i][1][r] + b1;
      float v2 = acc[i][2][r] + b2;
      float v3 = acc[i][3][r] + b3;
      int b = m >> 11, s = m & 2047;
      size_t off = ((size_t)((b << 4) + h) * 2048 + s) * 64;
      if (wh == 2) {                   // V -> f16
        union { _Float16 h2; u16 u; } c0, c1, c2, c3;
        c0.h2 = (_Float16)v0; c1.h2 = (_Float16)v1;
        c2.h2 = (_Float16)v2; c3.h2 = (_Float16)v3;
        dst[off + lr]      = c0.u;
        dst[off + 16 + lr] = c1.u;
        dst[off + 32 + lr] = c2.u;
        dst[off + 48 + lr] = c3.u;
      } else {                         // RoPE via table; Q gets 1/8*log2(e)
        alignas(16) u16 rv[8];
        *(uint4*)rv = *(const uint4*)(RT + ((size_t)m * 16 + lr) * 8);
        float o0 = v0 * bf2f(rv[0]) - v2 * bf2f(rv[4]);
        float o1 = v1 * bf2f(rv[1]) - v3 * bf2f(rv[5]);
        float o2 = v2 * bf2f(rv[2]) + v0 * bf2f(rv[6]);
        float o3 = v3 * bf2f(rv[3]) + v1 * bf2f(rv[7]);
        float sc8 = (wh == 0) ? 0.1803368801f : 1.0f;
        dst[off + lr]      = f2bf(o0 * sc8);
        dst[off + 16 + lr] = f2bf(o1 * sc8);
        dst[off + 32 + lr] = f2bf(o2 * sc8);
        dst[off + 48 + lr] = f2bf(o3 * sc8);
      }
    }
}

// ---------------- V [B,H,S,D] -> Vt [B,H,D,S] (bit-moves) ------------------
__global__ __launch_bounds__(256) void vtrans_kernel(
    const u16* __restrict__ V, u16* __restrict__ Vt)
{
  __shared__ __align__(16) u16 T[64][LDT];
  const int bh = blockIdx.y;
  const int s0 = blockIdx.x * 64;
  const u16* src = V + ((size_t)bh * 2048 + s0) * 64;
  const int r = threadIdx.x >> 2;
  const int c = (threadIdx.x & 3) << 4;
  *(uint4*)(&T[r][c])     = *(const uint4*)(src + r * 64 + c);
  *(uint4*)(&T[r][c + 8]) = *(const uint4*)(src + r * 64 + c + 8);
  __syncthreads();
  alignas(16) u16 tmp[16];
#pragma unroll
  for (int j = 0; j < 16; ++j) tmp[j] = T[c + j][r];
  u16* dst = Vt + ((size_t)bh * 64 + r) * 2048 + s0 + c;
  *(uint4*)(dst)     = *(uint4*)(&tmp[0]);
  *(uint4*)(dst + 8) = *(uint4*)(&tmp[8]);
}

// ---- attention: S^T trick, double-buffered staging, 1 barrier/iter --------
__device__ __forceinline__ void attn_stage(
    const u16* __restrict__ Kh, const u16* __restrict__ Vh, int kv0,
    u16* KsB, u16* VsB, int w, int lrow, int lcol8)
{
#pragma unroll
  for (int p = 0; p < 2; ++p) {
    int base = w * 16 + p * 8;
    int rr = base + lrow;
    int cc = (lcol8 ^ (rr & 7)) << 3;
    glds16(Kh + (size_t)(kv0 + rr) * 64 + cc, KsB + base * 64);
    glds16(Vh + (size_t)rr * 2048 + kv0 + cc, VsB + base * 64);
  }
}

__global__ __launch_bounds__(256, 4) void attn_kernel(
    const u16* __restrict__ Q, const u16* __restrict__ K,
    const u16* __restrict__ Vt, u16* __restrict__ O)
{
  __shared__ __align__(16) u16 Ks[2][64 * 64];
  __shared__ __align__(16) u16 Vs[2][64 * 64];
  // XCD-clustering remap: all 16 q-blocks of one (b,h) land on one XCD.
  const int flat = blockIdx.x + (blockIdx.y << 4);   // 0..1023
  const int xcd = flat & 7, j = flat >> 3;           // j in 0..127
  const int bh = (xcd << 3) + (j & 7);               // bijective
  const int q0 = (j >> 3) << 7;
  const int b = bh >> 4, h = bh & 15;
  const u16* Qh = Q  + (size_t)bh * (2048 * 64);
  const u16* Kh = K  + (size_t)bh * (2048 * 64);
  const u16* Vh = Vt + (size_t)bh * (64 * 2048);
  const int tid = threadIdx.x, lane = tid & 63, w = tid >> 6;
  const int lr = lane & 15, lq = lane >> 4;
  const int lrow = lane >> 3, lcol8 = lane & 7;
  const int wq0 = w * 32;

  // prefetch tile 0
  attn_stage(Kh, Vh, 0, Ks[0], Vs[0], w, lrow, lcol8);

  // Q fragments: iter-invariant, straight from global (B-operand, n=q)
  bf16x8 qa[2][2];
#pragma unroll
  for (int mi = 0; mi < 2; ++mi)
#pragma unroll
    for (int kx = 0; kx < 2; ++kx)
      qa[mi][kx] = *(const bf16x8*)(Qh + (size_t)(q0 + wq0 + mi * 16 + lr) * 64 + kx * 32 + lq * 8);

  const f32x4 Z = (f32x4){0.f, 0.f, 0.f, 0.f};   // shared zero C-in
  const f16x8 ones = {(_Float16)1.f, (_Float16)1.f, (_Float16)1.f, (_Float16)1.f,
                      (_Float16)1.f, (_Float16)1.f, (_Float16)1.f, (_Float16)1.f};

  f32x4 acc_o[2][4];
  f32x4 ssum[2];                                  // P row-sums via MFMA
#pragma unroll
  for (int mi = 0; mi < 2; ++mi) {
    ssum[mi] = (f32x4){0.f, 0.f, 0.f, 0.f};
#pragma unroll
    for (int td = 0; td < 4; ++td) acc_o[mi][td] = (f32x4){0.f, 0.f, 0.f, 0.f};
  }

  for (int it = 0; it < 32; ++it) {
    const int cur = it & 1;
    __syncthreads();                       // drains staging of buf(cur)
    if (it + 1 < 32)                       // prefetch next into other buffer
      attn_stage(Kh, Vh, (it + 1) << 6, Ks[cur ^ 1], Vs[cur ^ 1], w, lrow, lcol8);
    const u16* Kc = Ks[cur];
    const u16* Vc = Vs[cur];

    // S^T = K Q^T : tiles [kv=tj*16][q=mi*16], contraction over d
    f32x4 st[4][2];
#pragma unroll
    for (int kx = 0; kx < 2; ++kx) {
      bf16x8 ka[4];
#pragma unroll
      for (int tj = 0; tj < 4; ++tj) {
        int row = tj * 16 + lr;
        ka[tj] = *(const bf16x8*)(&Kc[row * 64 + ((((kx << 2) + lq) ^ (lr & 7)) << 3)]);
      }
#pragma unroll
      for (int tj = 0; tj < 4; ++tj)
#pragma unroll
        for (int mi = 0; mi < 2; ++mi)
          st[tj][mi] = __builtin_amdgcn_mfma_f32_16x16x32_bf16(
              ka[tj], qa[mi][kx], kx ? st[tj][mi] : Z, 0, 0, 0);
    }

    // p = 2^s (log2e pre-folded into Q). Build K=32 f16 A-frags via
    // 2x permlane32_swap + 2x permlane16_swap lq-transpose.
    f16x8 pa[2][2];
#pragma unroll
    for (int mi = 0; mi < 2; ++mi)
#pragma unroll
      for (int t32 = 0; t32 < 2; ++t32) {
        unsigned dw[4];
#pragma unroll
        for (int tt = 0; tt < 2; ++tt) {
          const int tj = t32 * 2 + tt;
          float e0 = __builtin_amdgcn_exp2f(st[tj][mi][0]);
          float e1 = __builtin_amdgcn_exp2f(st[tj][mi][1]);
          float e2 = __builtin_amdgcn_exp2f(st[tj][mi][2]);
          float e3 = __builtin_amdgcn_exp2f(st[tj][mi][3]);
          dw[tt * 2 + 0] = pkrtz_u32(e0, e1);   // kv_local lq*4+{0,1}
          dw[tt * 2 + 1] = pkrtz_u32(e2, e3);   // kv_local lq*4+{2,3}
        }
        pswap32(dw[0], dw[2]);
        pswap32(dw[1], dw[3]);
        pswap16(dw[0], dw[2]);
        pswap16(dw[1], dw[3]);
        union { unsigned u[4]; f16x8 v; } P;
        P.u[0] = dw[0]; P.u[1] = dw[1]; P.u[2] = dw[2]; P.u[3] = dw[3];
        pa[mi][t32] = P.v;
      }

    // O += P V; row-sums ride the matrix pipe after the PV MFMAs.
#pragma unroll
    for (int t32 = 0; t32 < 2; ++t32) {
      f16x8 bv[4];
#pragma unroll
      for (int td = 0; td < 4; ++td) {
        int row = td * 16 + lr;
        bv[td] = *(const f16x8*)(&Vc[row * 64 + ((((t32 << 2) + lq) ^ (lr & 7)) << 3)]);
      }
#pragma unroll
      for (int td = 0; td < 4; ++td)
#pragma unroll
        for (int mi = 0; mi < 2; ++mi)
          acc_o[mi][td] = __builtin_amdgcn_mfma_f32_16x16x32_f16(pa[mi][t32], bv[td], acc_o[mi][td], 0, 0, 0);
#pragma unroll
      for (int mi = 0; mi < 2; ++mi)
        ssum[mi] = __builtin_amdgcn_mfma_f32_16x16x32_f16(pa[mi][t32], ones, ssum[mi], 0, 0, 0);
    }
  }

  // ssum[mi][r] holds the denom for q-row lq*4+r (all lr identical)
#pragma unroll
  for (int mi = 0; mi < 2; ++mi)
#pragma unroll
    for (int r = 0; r < 4; ++r) {
      float inv = 1.f / ssum[mi][r];
      int qq = q0 + wq0 + mi * 16 + lq * 4 + r;
#pragma unroll
      for (int td = 0; td < 4; ++td) {
        int d = td * 16 + lr;
        O[(size_t)(b * 2048 + qq) * 1024 + h * 64 + d] = f2bf(acc_o[mi][td][r] * inv);
      }
    }
}

// ---------------- output projection (fp32 out) -----------------------------
__global__ __launch_bounds__(256) void proj_gemm_kernel(
    const u16* __restrict__ X, const u16* __restrict__ wp,
    const float* __restrict__ bias, float* __restrict__ out)
{
  __shared__ __align__(16) u16 As[2][128 * 32];
  __shared__ __align__(16) u16 Bs[2][128 * 32];
  f32x4 acc[4][4];
#pragma unroll
  for (int i = 0; i < 4; ++i)
#pragma unroll
    for (int j = 0; j < 4; ++j) acc[i][j] = (f32x4){0.f, 0.f, 0.f, 0.f};

  // Same XCD locality remap (8 col-blocks per row-panel here).
  const int flat = blockIdx.x + (blockIdx.y << 3);   // 0..511, x fastest
  const int xcd = flat & 7, j = flat >> 3;           // j in 0..63
  const int row0 = (xcd + (j & ~7)) << 7;            // m-panel = xcd + 8*(j/8)
  const int col0 = (j & 7) << 7;
  gemm_core_32(X, wp, 1024, row0, col0, As, Bs, acc);

  const int lane = threadIdx.x & 63;
  const int w = threadIdx.x >> 6;
  const int wm = (w >> 1) << 6, wn = (w & 1) << 6;
#pragma unroll
  for (int i = 0; i < 4; ++i)
#pragma unroll
    for (int j2 = 0; j2 < 4; ++j2)
#pragma unroll
      for (int r = 0; r < 4; ++r) {
        int m = row0 + wm + i * 16 + ((lane >> 4) << 2) + r;
        int n = col0 + wn + j2 * 16 + (lane & 15);
        out[(size_t)m * 1024 + n] = acc[i][j2][r] + bias[n];
      }
}

extern "C" void kernel_launch(void* const* d_in, const int* in_sizes, int n_in,
                              void* d_out, int out_size, void* d_ws, size_t ws_size,
                              hipStream_t stream)
{
  const float* hs   = (const float*)d_in[0];
  const float* cs   = (const float*)d_in[1];
  const float* sn   = (const float*)d_in[2];
  const float* qkvw = (const float*)d_in[3];
  const float* qkvb = (const float*)d_in[4];
  const float* pw   = (const float*)d_in[5];
  const float* pb   = (const float*)d_in[6];
  float* out = (float*)d_out;

  const size_t NQ = (size_t)8192 * 1024;
  u16* hsb   = (u16*)d_ws;
  u16* qkvwb = hsb + NQ;
  u16* pwb   = qkvwb + 3145728;
  u16* Qb    = pwb + 1048576;
  u16* Kb    = Qb + NQ;
  u16* Vb    = Kb + NQ;      // f16
  u16* Vtb   = Vb + NQ;      // f16
  u16* RT    = Vtb + NQ;     // rope table, 8192*16*8 u16 = 2 MB
  u16* Ob    = hsb;          // alias: hs consumed after qkv

  prep_kernel<<<12800, 256, 0, stream>>>(hs, qkvw, pw, cs, sn,
                                         hsb, qkvwb, pwb, RT);

  qkv_gemm_kernel<<<dim3(24, 64), 256, 0, stream>>>(hsb, qkvwb, qkvb, RT, Qb, Kb, Vb);
  vtrans_kernel<<<dim3(32, 64), 256, 0, stream>>>(Vb, Vtb);
  attn_kernel<<<dim3(16, 64), 256, 0, stream>>>(Qb, Kb, Vtb, Ob);
  proj_gemm_kernel<<<dim3(8, 64), 256, 0, stream>>>(Ob, pwb, pb, out);
}

// Round 11
// 275.248 us; speedup vs baseline: 1.1429x; 1.0834x over previous
//
#include <hip/hip_runtime.h>
#include <hip/hip_bf16.h>

// ViT attention, B=4 S=2048 C=1024 H=16 D=64. fp32 I/O, bf16/f16 MFMA inside.
// cast -> rope_table -> qkv_gemm(+bias+rope+scale) -> vtrans -> attn -> proj.
// R1: PV 16x16x32_f16 via permlane lq-transpose.  R3: ssum ones-MFMA +
//     zero-C + XCD remap (attn) + s_nop hazard fix.  R4/R5/R6: GEMM schedule
//     reworks all neutral.  R7: XCD locality remap for GEMMs (+4%, best=287).
// R8/R9: NT stores -> slower, reverted.  R10: BK=32 occupancy attack ->
//     regression, reverted. KEY R10 CLUE: VALUBusy(50) = 2x MfmaUtil(25) --
//     VALU:MFMA issue ratio caps the matrix pipe, invariant to scheduling.
// R11: compile-time K GEMM core: template<K>, per-thread base pointers
//     hoisted, K-loop fully unrolled -> glds addresses become base+const
//     (folds into offset imm), ds_read addresses computed once. Steady-state
//     VALU ~0. Single variable vs R7.

typedef unsigned short u16;
using bf16x8 = __attribute__((ext_vector_type(8))) __bf16;
using f32x4  = __attribute__((ext_vector_type(4))) float;
using f16x8  = __attribute__((ext_vector_type(8))) _Float16;
using fp16v2 = __attribute__((ext_vector_type(2))) __fp16;   // cvt_pkrtz native

#define LDT 80  // vtrans LDS pad only

__device__ __forceinline__ u16 f2bf(float f) {
  union { float f; unsigned u; } un; un.f = f;
  unsigned r = un.u + 0x7FFFu + ((un.u >> 16) & 1u);  // RNE
  return (u16)(r >> 16);
}
__device__ __forceinline__ float bf2f(u16 b) {
  union { unsigned u; float f; } un; un.u = ((unsigned)b) << 16;
  return un.f;
}

// pack two f32 -> two f16 (RTZ) into one dword
__device__ __forceinline__ unsigned pkrtz_u32(float a, float b) {
  union { fp16v2 v; unsigned u; } un;
  un.v = __builtin_amdgcn_cvt_pkrtz(a, b);
  return un.u;
}

// x' = [x.lo32, y.lo32]; y' = [x.hi32, y.hi32]  (gather 32-lane halves)
__device__ __forceinline__ void pswap32(unsigned &x, unsigned &y) {
  asm volatile("v_permlane32_swap_b32 %0, %1" : "+v"(x), "+v"(y));
}
// rows of 16 lanes: x' = [x0,y0,x2,y2]; y' = [x1,y1,x3,y3]
// s_nop 1 embedded: final writers of pa regs; hazard recognizer cannot see
// VALU-write->MFMA-read wait states for INLINEASM producers (R2 NaN cause).
__device__ __forceinline__ void pswap16(unsigned &x, unsigned &y) {
  asm volatile("v_permlane16_swap_b32 %0, %1\n\ts_nop 1" : "+v"(x), "+v"(y));
}

// async 16B/lane global -> LDS (lands at ldsbase + lane*16)
__device__ __forceinline__ void glds16(const void* g, void* l) {
  __builtin_amdgcn_global_load_lds(
      (__attribute__((address_space(1))) void*)(g),
      (__attribute__((address_space(3))) void*)(l), 16, 0, 0);
}

// ---------------- fp32 -> bf16 cast (vectorized x4) ------------------------
__global__ __launch_bounds__(256) void f2bf_kernel(
    const float* __restrict__ src, u16* __restrict__ dst, int n4)
{
  int i = blockIdx.x * 256 + threadIdx.x;
  if (i < n4) {
    float4 v = ((const float4*)src)[i];
    ushort4 o;
    o.x = f2bf(v.x); o.y = f2bf(v.y); o.z = f2bf(v.z); o.w = f2bf(v.w);
    ((ushort4*)dst)[i] = o;
  }
}

// ------- RoPE table: RT[m][lr] = {cos[m][lr+16j]}{sin[m][lr+16j]} bf16 -----
__global__ __launch_bounds__(256) void rope_table_kernel(
    const float* __restrict__ cs, const float* __restrict__ sn,
    u16* __restrict__ RT)
{
  int t = blockIdx.x * 256 + threadIdx.x;   // 8192*16 = 131072 exact
  int lr = t & 15, m = t >> 4;
  const float* c = cs + (size_t)m * 64;
  const float* s = sn + (size_t)m * 64;
  alignas(16) u16 o[8];
  o[0] = f2bf(c[lr]); o[1] = f2bf(c[lr + 16]);
  o[2] = f2bf(c[lr + 32]); o[3] = f2bf(c[lr + 48]);
  o[4] = f2bf(s[lr]); o[5] = f2bf(s[lr + 16]);
  o[6] = f2bf(s[lr + 32]); o[7] = f2bf(s[lr + 48]);
  *(uint4*)(RT + (size_t)t * 8) = *(const uint4*)o;
}

// ------ 128x128 BT-GEMM core, compile-time K, counted-vmcnt dbuf -----------
__device__ __forceinline__ void gemm_compute_128(
    const u16* __restrict__ Asc, const u16* __restrict__ Bsc,
    int wm, int wn, int lr, int lq, f32x4 acc[4][4])
{
#pragma unroll
  for (int kx = 0; kx < 2; ++kx) {
    bf16x8 af[4], bv[4];
    const int sl = (((kx << 2) + lq) ^ (lr & 7)) << 3;
#pragma unroll
    for (int i = 0; i < 4; ++i) {
      af[i] = *(const bf16x8*)(&Asc[(wm + i * 16 + lr) * 64 + sl]);
      bv[i] = *(const bf16x8*)(&Bsc[(wn + i * 16 + lr) * 64 + sl]);
    }
#pragma unroll
    for (int i = 0; i < 4; ++i)
#pragma unroll
      for (int j = 0; j < 4; ++j)
        acc[i][j] = __builtin_amdgcn_mfma_f32_16x16x32_bf16(af[i], bv[j], acc[i][j], 0, 0, 0);
  }
}

// Template K: full unroll of the K-loop. Per-thread global base pointers
// computed ONCE; after unrolling each glds address is base + compile-time
// constant (folds into the instruction's offset immediate). The two LDS
// buffers are compile-time-alternating constants -> ds_read/write addresses
// are loop-invariant. Steady-state VALU ~0 (the R10 50%-VALUBusy fix).
template<int K>
__device__ __forceinline__ void gemm_core_128(
    const u16* __restrict__ A, const u16* __restrict__ Bm,
    int row0, int col0, u16 (*As)[128 * 64], u16 (*Bs)[128 * 64],
    f32x4 acc[4][4])
{
  const int tid = threadIdx.x;
  const int lane = tid & 63;
  const int w  = tid >> 6;
  const int wm = (w >> 1) << 6;
  const int wn = (w & 1) << 6;
  const int lr = lane & 15;
  const int lq = lane >> 4;
  const int lrow = lane >> 3;
  const int lcol8 = lane & 7;
  constexpr int nk = K >> 6;

  const u16* aP[4];
  const u16* bP[4];
  u16* la[4];
  u16* lb[4];
#pragma unroll
  for (int p = 0; p < 4; ++p) {
    int base = w * 32 + p * 8;
    int rr = base + lrow;
    int cc = (lcol8 ^ (rr & 7)) << 3;
    aP[p] = A  + (size_t)(row0 + rr) * K + cc;
    bP[p] = Bm + (size_t)(col0 + rr) * K + cc;
    la[p] = (u16*)&As[0][base * 64];   // buffer 1 = +128*64 (const delta)
    lb[p] = (u16*)&Bs[0][base * 64];
  }

#pragma unroll
  for (int p = 0; p < 4; ++p) {
    glds16(aP[p], la[p]);
    glds16(bP[p], lb[p]);
  }

#pragma unroll
  for (int ks = 0; ks < nk - 1; ++ks) {
    const int nxt = (ks + 1) & 1;        // compile-time after unroll
#pragma unroll
    for (int p = 0; p < 4; ++p) {
      glds16(aP[p] + (ks + 1) * 64, la[p] + nxt * (128 * 64));
      glds16(bP[p] + (ks + 1) * 64, lb[p] + nxt * (128 * 64));
    }
    asm volatile("s_waitcnt vmcnt(8)" ::: "memory");  // 8 newest fly on
    __builtin_amdgcn_s_barrier();
    __builtin_amdgcn_sched_barrier(0);   // no ds_read hoists above barrier
    gemm_compute_128(As[ks & 1], Bs[ks & 1], wm, wn, lr, lq, acc);
    __builtin_amdgcn_sched_barrier(0);   // no compute sinks below barrier
    __builtin_amdgcn_s_barrier();
  }
  asm volatile("s_waitcnt vmcnt(0)" ::: "memory");    // last tile drain
  __builtin_amdgcn_s_barrier();
  __builtin_amdgcn_sched_barrier(0);
  gemm_compute_128(As[(nk - 1) & 1], Bs[(nk - 1) & 1], wm, wn, lr, lq, acc);
}

// ------- QKV projection + bias + fused RoPE (table) + scale ----------------
__global__ __launch_bounds__(256) void qkv_gemm_kernel(
    const u16* __restrict__ hs, const u16* __restrict__ wq,
    const float* __restrict__ bias, const u16* __restrict__ RT,
    u16* __restrict__ Q, u16* __restrict__ K, u16* __restrict__ V)
{
  __shared__ __align__(16) u16 As[2][128 * 64];
  __shared__ __align__(16) u16 Bs[2][128 * 64];
  f32x4 acc[4][4];
#pragma unroll
  for (int i = 0; i < 4; ++i)
#pragma unroll
    for (int j = 0; j < 4; ++j) acc[i][j] = (f32x4){0.f, 0.f, 0.f, 0.f};

  // XCD locality remap (R7): each XCD runs complete row-panel runs.
  const int flat = blockIdx.x + blockIdx.y * 24;   // 0..1535, x fastest
  const int xcd = flat & 7, j = flat >> 3;         // j in 0..191
  const int row0 = (xcd + ((j / 24) << 3)) << 7;   // m-panel = xcd + 8*(j/24)
  const int col0 = (j % 24) << 7;                  // n in [0,3072)
  gemm_core_128<1024>(hs, wq, row0, col0, As, Bs, acc);

  const int lane = threadIdx.x & 63;
  const int w = threadIdx.x >> 6;
  const int lr = lane & 15, lq = lane >> 4;
  const int wm = (w >> 1) << 6, wn = (w & 1) << 6;
  const int ncol = col0 + wn;          // 64-aligned -> single (wh,h)
  const int wh = ncol >> 10;           // 0=q 1=k 2=v (wave-uniform)
  const int h  = (ncol & 1023) >> 6;
  u16* dst = (wh == 0) ? Q : ((wh == 1) ? K : V);
  const float b0 = bias[ncol + lr];
  const float b1 = bias[ncol + 16 + lr];
  const float b2 = bias[ncol + 32 + lr];
  const float b3 = bias[ncol + 48 + lr];

#pragma unroll
  for (int i = 0; i < 4; ++i)
#pragma unroll
    for (int r = 0; r < 4; ++r) {
      int m = row0 + wm + i * 16 + lq * 4 + r;   // = b*2048 + s
      float v0 = acc[i][0][r] + b0;
      float v1 = acc[i][1][r] + b1;
      float v2 = acc[i][2][r] + b2;
      float v3 = acc[i][3][r] + b3;
      int b = m >> 11, s = m & 2047;
      size_t off = ((size_t)((b << 4) + h) * 2048 + s) * 64;
      if (wh == 2) {                   // V -> f16
        union { _Float16 h2; u16 u; } c0, c1, c2, c3;
        c0.h2 = (_Float16)v0; c1.h2 = (_Float16)v1;
        c2.h2 = (_Float16)v2; c3.h2 = (_Float16)v3;
        dst[off + lr]      = c0.u;
        dst[off + 16 + lr] = c1.u;
        dst[off + 32 + lr] = c2.u;
        dst[off + 48 + lr] = c3.u;
      } else {                         // RoPE via table; Q gets 1/8*log2(e)
        alignas(16) u16 rv[8];
        *(uint4*)rv = *(const uint4*)(RT + ((size_t)m * 16 + lr) * 8);
        float o0 = v0 * bf2f(rv[0]) - v2 * bf2f(rv[4]);
        float o1 = v1 * bf2f(rv[1]) - v3 * bf2f(rv[5]);
        float o2 = v2 * bf2f(rv[2]) + v0 * bf2f(rv[6]);
        float o3 = v3 * bf2f(rv[3]) + v1 * bf2f(rv[7]);
        float sc8 = (wh == 0) ? 0.1803368801f : 1.0f;
        dst[off + lr]      = f2bf(o0 * sc8);
        dst[off + 16 + lr] = f2bf(o1 * sc8);
        dst[off + 32 + lr] = f2bf(o2 * sc8);
        dst[off + 48 + lr] = f2bf(o3 * sc8);
      }
    }
}

// ---------------- V [B,H,S,D] -> Vt [B,H,D,S] (bit-moves) ------------------
__global__ __launch_bounds__(256) void vtrans_kernel(
    const u16* __restrict__ V, u16* __restrict__ Vt)
{
  __shared__ __align__(16) u16 T[64][LDT];
  const int bh = blockIdx.y;
  const int s0 = blockIdx.x * 64;
  const u16* src = V + ((size_t)bh * 2048 + s0) * 64;
  const int r = threadIdx.x >> 2;
  const int c = (threadIdx.x & 3) << 4;
  *(uint4*)(&T[r][c])     = *(const uint4*)(src + r * 64 + c);
  *(uint4*)(&T[r][c + 8]) = *(const uint4*)(src + r * 64 + c + 8);
  __syncthreads();
  alignas(16) u16 tmp[16];
#pragma unroll
  for (int j = 0; j < 16; ++j) tmp[j] = T[c + j][r];
  u16* dst = Vt + ((size_t)bh * 64 + r) * 2048 + s0 + c;
  *(uint4*)(dst)     = *(uint4*)(&tmp[0]);
  *(uint4*)(dst + 8) = *(uint4*)(&tmp[8]);
}

// ---- attention: S^T trick, double-buffered staging, 1 barrier/iter --------
__device__ __forceinline__ void attn_stage(
    const u16* __restrict__ Kh, const u16* __restrict__ Vh, int kv0,
    u16* KsB, u16* VsB, int w, int lrow, int lcol8)
{
#pragma unroll
  for (int p = 0; p < 2; ++p) {
    int base = w * 16 + p * 8;
    int rr = base + lrow;
    int cc = (lcol8 ^ (rr & 7)) << 3;
    glds16(Kh + (size_t)(kv0 + rr) * 64 + cc, KsB + base * 64);
    glds16(Vh + (size_t)rr * 2048 + kv0 + cc, VsB + base * 64);
  }
}

__global__ __launch_bounds__(256, 4) void attn_kernel(
    const u16* __restrict__ Q, const u16* __restrict__ K,
    const u16* __restrict__ Vt, u16* __restrict__ O)
{
  __shared__ __align__(16) u16 Ks[2][64 * 64];
  __shared__ __align__(16) u16 Vs[2][64 * 64];
  // XCD-clustering remap: all 16 q-blocks of one (b,h) land on one XCD.
  const int flat = blockIdx.x + (blockIdx.y << 4);   // 0..1023
  const int xcd = flat & 7, j = flat >> 3;           // j in 0..127
  const int bh = (xcd << 3) + (j & 7);               // bijective
  const int q0 = (j >> 3) << 7;
  const int b = bh >> 4, h = bh & 15;
  const u16* Qh = Q  + (size_t)bh * (2048 * 64);
  const u16* Kh = K  + (size_t)bh * (2048 * 64);
  const u16* Vh = Vt + (size_t)bh * (64 * 2048);
  const int tid = threadIdx.x, lane = tid & 63, w = tid >> 6;
  const int lr = lane & 15, lq = lane >> 4;
  const int lrow = lane >> 3, lcol8 = lane & 7;
  const int wq0 = w * 32;

  // prefetch tile 0
  attn_stage(Kh, Vh, 0, Ks[0], Vs[0], w, lrow, lcol8);

  // Q fragments: iter-invariant, straight from global (B-operand, n=q)
  bf16x8 qa[2][2];
#pragma unroll
  for (int mi = 0; mi < 2; ++mi)
#pragma unroll
    for (int kx = 0; kx < 2; ++kx)
      qa[mi][kx] = *(const bf16x8*)(Qh + (size_t)(q0 + wq0 + mi * 16 + lr) * 64 + kx * 32 + lq * 8);

  const f32x4 Z = (f32x4){0.f, 0.f, 0.f, 0.f};   // shared zero C-in
  const f16x8 ones = {(_Float16)1.f, (_Float16)1.f, (_Float16)1.f, (_Float16)1.f,
                      (_Float16)1.f, (_Float16)1.f, (_Float16)1.f, (_Float16)1.f};

  f32x4 acc_o[2][4];
  f32x4 ssum[2];                                  // P row-sums via MFMA
#pragma unroll
  for (int mi = 0; mi < 2; ++mi) {
    ssum[mi] = (f32x4){0.f, 0.f, 0.f, 0.f};
#pragma unroll
    for (int td = 0; td < 4; ++td) acc_o[mi][td] = (f32x4){0.f, 0.f, 0.f, 0.f};
  }

  for (int it = 0; it < 32; ++it) {
    const int cur = it & 1;
    __syncthreads();                       // drains staging of buf(cur)
    if (it + 1 < 32)                       // prefetch next into other buffer
      attn_stage(Kh, Vh, (it + 1) << 6, Ks[cur ^ 1], Vs[cur ^ 1], w, lrow, lcol8);
    const u16* Kc = Ks[cur];
    const u16* Vc = Vs[cur];

    // S^T = K Q^T : tiles [kv=tj*16][q=mi*16], contraction over d
    f32x4 st[4][2];
#pragma unroll
    for (int kx = 0; kx < 2; ++kx) {
      bf16x8 ka[4];
#pragma unroll
      for (int tj = 0; tj < 4; ++tj) {
        int row = tj * 16 + lr;
        ka[tj] = *(const bf16x8*)(&Kc[row * 64 + ((((kx << 2) + lq) ^ (lr & 7)) << 3)]);
      }
#pragma unroll
      for (int tj = 0; tj < 4; ++tj)
#pragma unroll
        for (int mi = 0; mi < 2; ++mi)
          st[tj][mi] = __builtin_amdgcn_mfma_f32_16x16x32_bf16(
              ka[tj], qa[mi][kx], kx ? st[tj][mi] : Z, 0, 0, 0);
    }

    // p = 2^s (log2e pre-folded into Q). Build K=32 f16 A-frags via
    // 2x permlane32_swap + 2x permlane16_swap lq-transpose.
    f16x8 pa[2][2];
#pragma unroll
    for (int mi = 0; mi < 2; ++mi)
#pragma unroll
      for (int t32 = 0; t32 < 2; ++t32) {
        unsigned dw[4];
#pragma unroll
        for (int tt = 0; tt < 2; ++tt) {
          const int tj = t32 * 2 + tt;
          float e0 = __builtin_amdgcn_exp2f(st[tj][mi][0]);
          float e1 = __builtin_amdgcn_exp2f(st[tj][mi][1]);
          float e2 = __builtin_amdgcn_exp2f(st[tj][mi][2]);
          float e3 = __builtin_amdgcn_exp2f(st[tj][mi][3]);
          dw[tt * 2 + 0] = pkrtz_u32(e0, e1);   // kv_local lq*4+{0,1}
          dw[tt * 2 + 1] = pkrtz_u32(e2, e3);   // kv_local lq*4+{2,3}
        }
        pswap32(dw[0], dw[2]);
        pswap32(dw[1], dw[3]);
        pswap16(dw[0], dw[2]);
        pswap16(dw[1], dw[3]);
        union { unsigned u[4]; f16x8 v; } P;
        P.u[0] = dw[0]; P.u[1] = dw[1]; P.u[2] = dw[2]; P.u[3] = dw[3];
        pa[mi][t32] = P.v;
      }

    // O += P V; row-sums ride the matrix pipe after the PV MFMAs.
#pragma unroll
    for (int t32 = 0; t32 < 2; ++t32) {
      f16x8 bv[4];
#pragma unroll
      for (int td = 0; td < 4; ++td) {
        int row = td * 16 + lr;
        bv[td] = *(const f16x8*)(&Vc[row * 64 + ((((t32 << 2) + lq) ^ (lr & 7)) << 3)]);
      }
#pragma unroll
      for (int td = 0; td < 4; ++td)
#pragma unroll
        for (int mi = 0; mi < 2; ++mi)
          acc_o[mi][td] = __builtin_amdgcn_mfma_f32_16x16x32_f16(pa[mi][t32], bv[td], acc_o[mi][td], 0, 0, 0);
#pragma unroll
      for (int mi = 0; mi < 2; ++mi)
        ssum[mi] = __builtin_amdgcn_mfma_f32_16x16x32_f16(pa[mi][t32], ones, ssum[mi], 0, 0, 0);
    }
  }

  // ssum[mi][r] holds the denom for q-row lq*4+r (all lr identical)
#pragma unroll
  for (int mi = 0; mi < 2; ++mi)
#pragma unroll
    for (int r = 0; r < 4; ++r) {
      float inv = 1.f / ssum[mi][r];
      int qq = q0 + wq0 + mi * 16 + lq * 4 + r;
#pragma unroll
      for (int td = 0; td < 4; ++td) {
        int d = td * 16 + lr;
        O[(size_t)(b * 2048 + qq) * 1024 + h * 64 + d] = f2bf(acc_o[mi][td][r] * inv);
      }
    }
}

// ---------------- output projection (fp32 out) -----------------------------
__global__ __launch_bounds__(256) void proj_gemm_kernel(
    const u16* __restrict__ X, const u16* __restrict__ wp,
    const float* __restrict__ bias, float* __restrict__ out)
{
  __shared__ __align__(16) u16 As[2][128 * 64];
  __shared__ __align__(16) u16 Bs[2][128 * 64];
  f32x4 acc[4][4];
#pragma unroll
  for (int i = 0; i < 4; ++i)
#pragma unroll
    for (int j = 0; j < 4; ++j) acc[i][j] = (f32x4){0.f, 0.f, 0.f, 0.f};

  // Same XCD locality remap (8 col-blocks per row-panel here).
  const int flat = blockIdx.x + (blockIdx.y << 3);   // 0..511, x fastest
  const int xcd = flat & 7, j = flat >> 3;           // j in 0..63
  const int row0 = (xcd + (j & ~7)) << 7;            // m-panel = xcd + 8*(j/8)
  const int col0 = (j & 7) << 7;
  gemm_core_128<1024>(X, wp, row0, col0, As, Bs, acc);

  const int lane = threadIdx.x & 63;
  const int w = threadIdx.x >> 6;
  const int wm = (w >> 1) << 6, wn = (w & 1) << 6;
#pragma unroll
  for (int i = 0; i < 4; ++i)
#pragma unroll
    for (int j2 = 0; j2 < 4; ++j2)
#pragma unroll
      for (int r = 0; r < 4; ++r) {
        int m = row0 + wm + i * 16 + ((lane >> 4) << 2) + r;
        int n = col0 + wn + j2 * 16 + (lane & 15);
        out[(size_t)m * 1024 + n] = acc[i][j2][r] + bias[n];
      }
}

extern "C" void kernel_launch(void* const* d_in, const int* in_sizes, int n_in,
                              void* d_out, int out_size, void* d_ws, size_t ws_size,
                              hipStream_t stream)
{
  const float* hs   = (const float*)d_in[0];
  const float* cs   = (const float*)d_in[1];
  const float* sn   = (const float*)d_in[2];
  const float* qkvw = (const float*)d_in[3];
  const float* qkvb = (const float*)d_in[4];
  const float* pw   = (const float*)d_in[5];
  const float* pb   = (const float*)d_in[6];
  float* out = (float*)d_out;

  const size_t NQ = (size_t)8192 * 1024;
  u16* hsb   = (u16*)d_ws;
  u16* qkvwb = hsb + NQ;
  u16* pwb   = qkvwb + 3145728;
  u16* Qb    = pwb + 1048576;
  u16* Kb    = Qb + NQ;
  u16* Vb    = Kb + NQ;      // f16
  u16* Vtb   = Vb + NQ;      // f16
  u16* RT    = Vtb + NQ;     // rope table, 8192*16*8 u16 = 2 MB
  u16* Ob    = hsb;          // alias: hs consumed after qkv

  f2bf_kernel<<<8192, 256, 0, stream>>>(hs, hsb, (int)(NQ / 4));
  f2bf_kernel<<<3072, 256, 0, stream>>>(qkvw, qkvwb, 3145728 / 4);
  f2bf_kernel<<<1024, 256, 0, stream>>>(pw, pwb, 1048576 / 4);
  rope_table_kernel<<<512, 256, 0, stream>>>(cs, sn, RT);

  qkv_gemm_kernel<<<dim3(24, 64), 256, 0, stream>>>(hsb, qkvwb, qkvb, RT, Qb, Kb, Vb);
  vtrans_kernel<<<dim3(32, 64), 256, 0, stream>>>(Vb, Vtb);
  attn_kernel<<<dim3(16, 64), 256, 0, stream>>>(Qb, Kb, Vtb, Ob);
  proj_gemm_kernel<<<dim3(8, 64), 256, 0, stream>>>(Ob, pwb, pb, out);
}

// Round 12
// 271.786 us; speedup vs baseline: 1.1575x; 1.0127x over previous
//
#include <hip/hip_runtime.h>
#include <hip/hip_bf16.h>

// ViT attention, B=4 S=2048 C=1024 H=16 D=64. fp32 I/O, bf16/f16 MFMA inside.
// cast -> rope_table -> qkv_gemm(+bias+rope+scale) -> vtrans -> attn -> proj.
// R1: PV 16x16x32_f16 via permlane lq-transpose.  R3: ssum ones-MFMA +
//     zero-C + XCD remaps + s_nop hazard fix.  R7: GEMM XCD locality (+4%).
// R11: compile-time-K GEMM core (VALU addressing -> 0): 287 -> 275.  The
//      R10 diagnosis held: VALU:MFMA issue ratio was the cap, not latency.
// R12: same recipe on attn (now top at 82us, VALUBusy 52 > MfmaUtil 41,
//      sum=93% = issue-saturated): #pragma unroll 2 on the kv-loop (buffer
//      parity becomes compile-time -> ds_read addresses loop-invariant) +
//      persistent staging pointers bumped by constants. Single variable.

typedef unsigned short u16;
using bf16x8 = __attribute__((ext_vector_type(8))) __bf16;
using f32x4  = __attribute__((ext_vector_type(4))) float;
using f16x8  = __attribute__((ext_vector_type(8))) _Float16;
using fp16v2 = __attribute__((ext_vector_type(2))) __fp16;   // cvt_pkrtz native

#define LDT 80  // vtrans LDS pad only

__device__ __forceinline__ u16 f2bf(float f) {
  union { float f; unsigned u; } un; un.f = f;
  unsigned r = un.u + 0x7FFFu + ((un.u >> 16) & 1u);  // RNE
  return (u16)(r >> 16);
}
__device__ __forceinline__ float bf2f(u16 b) {
  union { unsigned u; float f; } un; un.u = ((unsigned)b) << 16;
  return un.f;
}

// pack two f32 -> two f16 (RTZ) into one dword
__device__ __forceinline__ unsigned pkrtz_u32(float a, float b) {
  union { fp16v2 v; unsigned u; } un;
  un.v = __builtin_amdgcn_cvt_pkrtz(a, b);
  return un.u;
}

// x' = [x.lo32, y.lo32]; y' = [x.hi32, y.hi32]  (gather 32-lane halves)
__device__ __forceinline__ void pswap32(unsigned &x, unsigned &y) {
  asm volatile("v_permlane32_swap_b32 %0, %1" : "+v"(x), "+v"(y));
}
// rows of 16 lanes: x' = [x0,y0,x2,y2]; y' = [x1,y1,x3,y3]
// s_nop 1 embedded: final writers of pa regs; hazard recognizer cannot see
// VALU-write->MFMA-read wait states for INLINEASM producers (R2 NaN cause).
__device__ __forceinline__ void pswap16(unsigned &x, unsigned &y) {
  asm volatile("v_permlane16_swap_b32 %0, %1\n\ts_nop 1" : "+v"(x), "+v"(y));
}

// async 16B/lane global -> LDS (lands at ldsbase + lane*16)
__device__ __forceinline__ void glds16(const void* g, void* l) {
  __builtin_amdgcn_global_load_lds(
      (__attribute__((address_space(1))) void*)(g),
      (__attribute__((address_space(3))) void*)(l), 16, 0, 0);
}

// ---------------- fp32 -> bf16 cast (vectorized x4) ------------------------
__global__ __launch_bounds__(256) void f2bf_kernel(
    const float* __restrict__ src, u16* __restrict__ dst, int n4)
{
  int i = blockIdx.x * 256 + threadIdx.x;
  if (i < n4) {
    float4 v = ((const float4*)src)[i];
    ushort4 o;
    o.x = f2bf(v.x); o.y = f2bf(v.y); o.z = f2bf(v.z); o.w = f2bf(v.w);
    ((ushort4*)dst)[i] = o;
  }
}

// ------- RoPE table: RT[m][lr] = {cos[m][lr+16j]}{sin[m][lr+16j]} bf16 -----
__global__ __launch_bounds__(256) void rope_table_kernel(
    const float* __restrict__ cs, const float* __restrict__ sn,
    u16* __restrict__ RT)
{
  int t = blockIdx.x * 256 + threadIdx.x;   // 8192*16 = 131072 exact
  int lr = t & 15, m = t >> 4;
  const float* c = cs + (size_t)m * 64;
  const float* s = sn + (size_t)m * 64;
  alignas(16) u16 o[8];
  o[0] = f2bf(c[lr]); o[1] = f2bf(c[lr + 16]);
  o[2] = f2bf(c[lr + 32]); o[3] = f2bf(c[lr + 48]);
  o[4] = f2bf(s[lr]); o[5] = f2bf(s[lr + 16]);
  o[6] = f2bf(s[lr + 32]); o[7] = f2bf(s[lr + 48]);
  *(uint4*)(RT + (size_t)t * 8) = *(const uint4*)o;
}

// ------ 128x128 BT-GEMM core, compile-time K, counted-vmcnt dbuf -----------
__device__ __forceinline__ void gemm_compute_128(
    const u16* __restrict__ Asc, const u16* __restrict__ Bsc,
    int wm, int wn, int lr, int lq, f32x4 acc[4][4])
{
#pragma unroll
  for (int kx = 0; kx < 2; ++kx) {
    bf16x8 af[4], bv[4];
    const int sl = (((kx << 2) + lq) ^ (lr & 7)) << 3;
#pragma unroll
    for (int i = 0; i < 4; ++i) {
      af[i] = *(const bf16x8*)(&Asc[(wm + i * 16 + lr) * 64 + sl]);
      bv[i] = *(const bf16x8*)(&Bsc[(wn + i * 16 + lr) * 64 + sl]);
    }
#pragma unroll
    for (int i = 0; i < 4; ++i)
#pragma unroll
      for (int j = 0; j < 4; ++j)
        acc[i][j] = __builtin_amdgcn_mfma_f32_16x16x32_bf16(af[i], bv[j], acc[i][j], 0, 0, 0);
  }
}

// Template K: full unroll; per-thread base pointers hoisted; glds addresses
// fold into offset immediates; steady-state VALU ~0 (R11).
template<int K>
__device__ __forceinline__ void gemm_core_128(
    const u16* __restrict__ A, const u16* __restrict__ Bm,
    int row0, int col0, u16 (*As)[128 * 64], u16 (*Bs)[128 * 64],
    f32x4 acc[4][4])
{
  const int tid = threadIdx.x;
  const int lane = tid & 63;
  const int w  = tid >> 6;
  const int wm = (w >> 1) << 6;
  const int wn = (w & 1) << 6;
  const int lr = lane & 15;
  const int lq = lane >> 4;
  const int lrow = lane >> 3;
  const int lcol8 = lane & 7;
  constexpr int nk = K >> 6;

  const u16* aP[4];
  const u16* bP[4];
  u16* la[4];
  u16* lb[4];
#pragma unroll
  for (int p = 0; p < 4; ++p) {
    int base = w * 32 + p * 8;
    int rr = base + lrow;
    int cc = (lcol8 ^ (rr & 7)) << 3;
    aP[p] = A  + (size_t)(row0 + rr) * K + cc;
    bP[p] = Bm + (size_t)(col0 + rr) * K + cc;
    la[p] = (u16*)&As[0][base * 64];   // buffer 1 = +128*64 (const delta)
    lb[p] = (u16*)&Bs[0][base * 64];
  }

#pragma unroll
  for (int p = 0; p < 4; ++p) {
    glds16(aP[p], la[p]);
    glds16(bP[p], lb[p]);
  }

#pragma unroll
  for (int ks = 0; ks < nk - 1; ++ks) {
    const int nxt = (ks + 1) & 1;        // compile-time after unroll
#pragma unroll
    for (int p = 0; p < 4; ++p) {
      glds16(aP[p] + (ks + 1) * 64, la[p] + nxt * (128 * 64));
      glds16(bP[p] + (ks + 1) * 64, lb[p] + nxt * (128 * 64));
    }
    asm volatile("s_waitcnt vmcnt(8)" ::: "memory");  // 8 newest fly on
    __builtin_amdgcn_s_barrier();
    __builtin_amdgcn_sched_barrier(0);   // no ds_read hoists above barrier
    gemm_compute_128(As[ks & 1], Bs[ks & 1], wm, wn, lr, lq, acc);
    __builtin_amdgcn_sched_barrier(0);   // no compute sinks below barrier
    __builtin_amdgcn_s_barrier();
  }
  asm volatile("s_waitcnt vmcnt(0)" ::: "memory");    // last tile drain
  __builtin_amdgcn_s_barrier();
  __builtin_amdgcn_sched_barrier(0);
  gemm_compute_128(As[(nk - 1) & 1], Bs[(nk - 1) & 1], wm, wn, lr, lq, acc);
}

// ------- QKV projection + bias + fused RoPE (table) + scale ----------------
__global__ __launch_bounds__(256) void qkv_gemm_kernel(
    const u16* __restrict__ hs, const u16* __restrict__ wq,
    const float* __restrict__ bias, const u16* __restrict__ RT,
    u16* __restrict__ Q, u16* __restrict__ K, u16* __restrict__ V)
{
  __shared__ __align__(16) u16 As[2][128 * 64];
  __shared__ __align__(16) u16 Bs[2][128 * 64];
  f32x4 acc[4][4];
#pragma unroll
  for (int i = 0; i < 4; ++i)
#pragma unroll
    for (int j = 0; j < 4; ++j) acc[i][j] = (f32x4){0.f, 0.f, 0.f, 0.f};

  // XCD locality remap (R7): each XCD runs complete row-panel runs.
  const int flat = blockIdx.x + blockIdx.y * 24;   // 0..1535, x fastest
  const int xcd = flat & 7, j = flat >> 3;         // j in 0..191
  const int row0 = (xcd + ((j / 24) << 3)) << 7;   // m-panel = xcd + 8*(j/24)
  const int col0 = (j % 24) << 7;                  // n in [0,3072)
  gemm_core_128<1024>(hs, wq, row0, col0, As, Bs, acc);

  const int lane = threadIdx.x & 63;
  const int w = threadIdx.x >> 6;
  const int lr = lane & 15, lq = lane >> 4;
  const int wm = (w >> 1) << 6, wn = (w & 1) << 6;
  const int ncol = col0 + wn;          // 64-aligned -> single (wh,h)
  const int wh = ncol >> 10;           // 0=q 1=k 2=v (wave-uniform)
  const int h  = (ncol & 1023) >> 6;
  u16* dst = (wh == 0) ? Q : ((wh == 1) ? K : V);
  const float b0 = bias[ncol + lr];
  const float b1 = bias[ncol + 16 + lr];
  const float b2 = bias[ncol + 32 + lr];
  const float b3 = bias[ncol + 48 + lr];

#pragma unroll
  for (int i = 0; i < 4; ++i)
#pragma unroll
    for (int r = 0; r < 4; ++r) {
      int m = row0 + wm + i * 16 + lq * 4 + r;   // = b*2048 + s
      float v0 = acc[i][0][r] + b0;
      float v1 = acc[i][1][r] + b1;
      float v2 = acc[i][2][r] + b2;
      float v3 = acc[i][3][r] + b3;
      int b = m >> 11, s = m & 2047;
      size_t off = ((size_t)((b << 4) + h) * 2048 + s) * 64;
      if (wh == 2) {                   // V -> f16
        union { _Float16 h2; u16 u; } c0, c1, c2, c3;
        c0.h2 = (_Float16)v0; c1.h2 = (_Float16)v1;
        c2.h2 = (_Float16)v2; c3.h2 = (_Float16)v3;
        dst[off + lr]      = c0.u;
        dst[off + 16 + lr] = c1.u;
        dst[off + 32 + lr] = c2.u;
        dst[off + 48 + lr] = c3.u;
      } else {                         // RoPE via table; Q gets 1/8*log2(e)
        alignas(16) u16 rv[8];
        *(uint4*)rv = *(const uint4*)(RT + ((size_t)m * 16 + lr) * 8);
        float o0 = v0 * bf2f(rv[0]) - v2 * bf2f(rv[4]);
        float o1 = v1 * bf2f(rv[1]) - v3 * bf2f(rv[5]);
        float o2 = v2 * bf2f(rv[2]) + v0 * bf2f(rv[6]);
        float o3 = v3 * bf2f(rv[3]) + v1 * bf2f(rv[7]);
        float sc8 = (wh == 0) ? 0.1803368801f : 1.0f;
        dst[off + lr]      = f2bf(o0 * sc8);
        dst[off + 16 + lr] = f2bf(o1 * sc8);
        dst[off + 32 + lr] = f2bf(o2 * sc8);
        dst[off + 48 + lr] = f2bf(o3 * sc8);
      }
    }
}

// ---------------- V [B,H,S,D] -> Vt [B,H,D,S] (bit-moves) ------------------
__global__ __launch_bounds__(256) void vtrans_kernel(
    const u16* __restrict__ V, u16* __restrict__ Vt)
{
  __shared__ __align__(16) u16 T[64][LDT];
  const int bh = blockIdx.y;
  const int s0 = blockIdx.x * 64;
  const u16* src = V + ((size_t)bh * 2048 + s0) * 64;
  const int r = threadIdx.x >> 2;
  const int c = (threadIdx.x & 3) << 4;
  *(uint4*)(&T[r][c])     = *(const uint4*)(src + r * 64 + c);
  *(uint4*)(&T[r][c + 8]) = *(const uint4*)(src + r * 64 + c + 8);
  __syncthreads();
  alignas(16) u16 tmp[16];
#pragma unroll
  for (int j = 0; j < 16; ++j) tmp[j] = T[c + j][r];
  u16* dst = Vt + ((size_t)bh * 64 + r) * 2048 + s0 + c;
  *(uint4*)(dst)     = *(uint4*)(&tmp[0]);
  *(uint4*)(dst + 8) = *(uint4*)(&tmp[8]);
}

// ---- attention: S^T trick, dbuf staging, unroll-2 + pointer bumps ---------
__global__ __launch_bounds__(256, 4) void attn_kernel(
    const u16* __restrict__ Q, const u16* __restrict__ K,
    const u16* __restrict__ Vt, u16* __restrict__ O)
{
  __shared__ __align__(16) u16 Ks[2][64 * 64];
  __shared__ __align__(16) u16 Vs[2][64 * 64];
  // XCD-clustering remap: all 16 q-blocks of one (b,h) land on one XCD.
  const int flat = blockIdx.x + (blockIdx.y << 4);   // 0..1023
  const int xcd = flat & 7, j = flat >> 3;           // j in 0..127
  const int bh = (xcd << 3) + (j & 7);               // bijective
  const int q0 = (j >> 3) << 7;
  const int b = bh >> 4, h = bh & 15;
  const u16* Qh = Q  + (size_t)bh * (2048 * 64);
  const u16* Kh = K  + (size_t)bh * (2048 * 64);
  const u16* Vh = Vt + (size_t)bh * (64 * 2048);
  const int tid = threadIdx.x, lane = tid & 63, w = tid >> 6;
  const int lr = lane & 15, lq = lane >> 4;
  const int lrow = lane >> 3, lcol8 = lane & 7;
  const int wq0 = w * 32;

  // Persistent staging pointers (R12): address math done ONCE; per-iter
  // cost is two constant bumps per pointer. LDS destinations are fixed
  // per (parity, p).
  const u16* kP[2];
  const u16* vP[2];
  u16* kD[2][2];
  u16* vD[2][2];
#pragma unroll
  for (int p = 0; p < 2; ++p) {
    int base = w * 16 + p * 8;
    int rr = base + lrow;
    int cc = (lcol8 ^ (rr & 7)) << 3;
    kP[p] = Kh + (size_t)rr * 64 + cc;     // += 4096/iter (64 rows * 64)
    vP[p] = Vh + (size_t)rr * 2048 + cc;   // += 64/iter (kv advance)
    kD[0][p] = &Ks[0][base * 64]; kD[1][p] = &Ks[1][base * 64];
    vD[0][p] = &Vs[0][base * 64]; vD[1][p] = &Vs[1][base * 64];
  }

  // prefetch tile 0 into buffer 0
#pragma unroll
  for (int p = 0; p < 2; ++p) {
    glds16(kP[p], kD[0][p]);
    glds16(vP[p], vD[0][p]);
    kP[p] += 4096;
    vP[p] += 64;
  }

  // Q fragments: iter-invariant, straight from global (B-operand, n=q)
  bf16x8 qa[2][2];
#pragma unroll
  for (int mi = 0; mi < 2; ++mi)
#pragma unroll
    for (int kx = 0; kx < 2; ++kx)
      qa[mi][kx] = *(const bf16x8*)(Qh + (size_t)(q0 + wq0 + mi * 16 + lr) * 64 + kx * 32 + lq * 8);

  const f32x4 Z = (f32x4){0.f, 0.f, 0.f, 0.f};   // shared zero C-in
  const f16x8 ones = {(_Float16)1.f, (_Float16)1.f, (_Float16)1.f, (_Float16)1.f,
                      (_Float16)1.f, (_Float16)1.f, (_Float16)1.f, (_Float16)1.f};

  f32x4 acc_o[2][4];
  f32x4 ssum[2];                                  // P row-sums via MFMA
#pragma unroll
  for (int mi = 0; mi < 2; ++mi) {
    ssum[mi] = (f32x4){0.f, 0.f, 0.f, 0.f};
#pragma unroll
    for (int td = 0; td < 4; ++td) acc_o[mi][td] = (f32x4){0.f, 0.f, 0.f, 0.f};
  }

  // unroll 2: buffer parity becomes compile-time -> the 16 swizzled ds_read
  // addresses per parity are loop-invariant VGPRs (computed once), killing
  // the per-iter VALU address recomputation (R10/R11 diagnosis).
#pragma unroll 2
  for (int it = 0; it < 32; ++it) {
    const int cur = it & 1;
    __syncthreads();                       // drains staging of buf(cur)
    if (it + 1 < 32) {                     // prefetch next into other buffer
#pragma unroll
      for (int p = 0; p < 2; ++p) {
        glds16(kP[p], kD[cur ^ 1][p]);
        glds16(vP[p], vD[cur ^ 1][p]);
        kP[p] += 4096;
        vP[p] += 64;
      }
    }
    const u16* Kc = Ks[cur];
    const u16* Vc = Vs[cur];

    // S^T = K Q^T : tiles [kv=tj*16][q=mi*16], contraction over d
    f32x4 st[4][2];
#pragma unroll
    for (int kx = 0; kx < 2; ++kx) {
      bf16x8 ka[4];
#pragma unroll
      for (int tj = 0; tj < 4; ++tj) {
        int row = tj * 16 + lr;
        ka[tj] = *(const bf16x8*)(&Kc[row * 64 + ((((kx << 2) + lq) ^ (lr & 7)) << 3)]);
      }
#pragma unroll
      for (int tj = 0; tj < 4; ++tj)
#pragma unroll
        for (int mi = 0; mi < 2; ++mi)
          st[tj][mi] = __builtin_amdgcn_mfma_f32_16x16x32_bf16(
              ka[tj], qa[mi][kx], kx ? st[tj][mi] : Z, 0, 0, 0);
    }

    // p = 2^s (log2e pre-folded into Q). Build K=32 f16 A-frags via
    // 2x permlane32_swap + 2x permlane16_swap lq-transpose.
    f16x8 pa[2][2];
#pragma unroll
    for (int mi = 0; mi < 2; ++mi)
#pragma unroll
      for (int t32 = 0; t32 < 2; ++t32) {
        unsigned dw[4];
#pragma unroll
        for (int tt = 0; tt < 2; ++tt) {
          const int tj = t32 * 2 + tt;
          float e0 = __builtin_amdgcn_exp2f(st[tj][mi][0]);
          float e1 = __builtin_amdgcn_exp2f(st[tj][mi][1]);
          float e2 = __builtin_amdgcn_exp2f(st[tj][mi][2]);
          float e3 = __builtin_amdgcn_exp2f(st[tj][mi][3]);
          dw[tt * 2 + 0] = pkrtz_u32(e0, e1);   // kv_local lq*4+{0,1}
          dw[tt * 2 + 1] = pkrtz_u32(e2, e3);   // kv_local lq*4+{2,3}
        }
        pswap32(dw[0], dw[2]);
        pswap32(dw[1], dw[3]);
        pswap16(dw[0], dw[2]);
        pswap16(dw[1], dw[3]);
        union { unsigned u[4]; f16x8 v; } P;
        P.u[0] = dw[0]; P.u[1] = dw[1]; P.u[2] = dw[2]; P.u[3] = dw[3];
        pa[mi][t32] = P.v;
      }

    // O += P V; row-sums ride the matrix pipe after the PV MFMAs.
#pragma unroll
    for (int t32 = 0; t32 < 2; ++t32) {
      f16x8 bv[4];
#pragma unroll
      for (int td = 0; td < 4; ++td) {
        int row = td * 16 + lr;
        bv[td] = *(const f16x8*)(&Vc[row * 64 + ((((t32 << 2) + lq) ^ (lr & 7)) << 3)]);
      }
#pragma unroll
      for (int td = 0; td < 4; ++td)
#pragma unroll
        for (int mi = 0; mi < 2; ++mi)
          acc_o[mi][td] = __builtin_amdgcn_mfma_f32_16x16x32_f16(pa[mi][t32], bv[td], acc_o[mi][td], 0, 0, 0);
#pragma unroll
      for (int mi = 0; mi < 2; ++mi)
        ssum[mi] = __builtin_amdgcn_mfma_f32_16x16x32_f16(pa[mi][t32], ones, ssum[mi], 0, 0, 0);
    }
  }

  // ssum[mi][r] holds the denom for q-row lq*4+r (all lr identical)
#pragma unroll
  for (int mi = 0; mi < 2; ++mi)
#pragma unroll
    for (int r = 0; r < 4; ++r) {
      float inv = 1.f / ssum[mi][r];
      int qq = q0 + wq0 + mi * 16 + lq * 4 + r;
#pragma unroll
      for (int td = 0; td < 4; ++td) {
        int d = td * 16 + lr;
        O[(size_t)(b * 2048 + qq) * 1024 + h * 64 + d] = f2bf(acc_o[mi][td][r] * inv);
      }
    }
}

// ---------------- output projection (fp32 out) -----------------------------
__global__ __launch_bounds__(256) void proj_gemm_kernel(
    const u16* __restrict__ X, const u16* __restrict__ wp,
    const float* __restrict__ bias, float* __restrict__ out)
{
  __shared__ __align__(16) u16 As[2][128 * 64];
  __shared__ __align__(16) u16 Bs[2][128 * 64];
  f32x4 acc[4][4];
#pragma unroll
  for (int i = 0; i < 4; ++i)
#pragma unroll
    for (int j = 0; j < 4; ++j) acc[i][j] = (f32x4){0.f, 0.f, 0.f, 0.f};

  // Same XCD locality remap (8 col-blocks per row-panel here).
  const int flat = blockIdx.x + (blockIdx.y << 3);   // 0..511, x fastest
  const int xcd = flat & 7, j = flat >> 3;           // j in 0..63
  const int row0 = (xcd + (j & ~7)) << 7;            // m-panel = xcd + 8*(j/8)
  const int col0 = (j & 7) << 7;
  gemm_core_128<1024>(X, wp, row0, col0, As, Bs, acc);

  const int lane = threadIdx.x & 63;
  const int w = threadIdx.x >> 6;
  const int wm = (w >> 1) << 6, wn = (w & 1) << 6;
#pragma unroll
  for (int i = 0; i < 4; ++i)
#pragma unroll
    for (int j2 = 0; j2 < 4; ++j2)
#pragma unroll
      for (int r = 0; r < 4; ++r) {
        int m = row0 + wm + i * 16 + ((lane >> 4) << 2) + r;
        int n = col0 + wn + j2 * 16 + (lane & 15);
        out[(size_t)m * 1024 + n] = acc[i][j2][r] + bias[n];
      }
}

extern "C" void kernel_launch(void* const* d_in, const int* in_sizes, int n_in,
                              void* d_out, int out_size, void* d_ws, size_t ws_size,
                              hipStream_t stream)
{
  const float* hs   = (const float*)d_in[0];
  const float* cs   = (const float*)d_in[1];
  const float* sn   = (const float*)d_in[2];
  const float* qkvw = (const float*)d_in[3];
  const float* qkvb = (const float*)d_in[4];
  const float* pw   = (const float*)d_in[5];
  const float* pb   = (const float*)d_in[6];
  float* out = (float*)d_out;

  const size_t NQ = (size_t)8192 * 1024;
  u16* hsb   = (u16*)d_ws;
  u16* qkvwb = hsb + NQ;
  u16* pwb   = qkvwb + 3145728;
  u16* Qb    = pwb + 1048576;
  u16* Kb    = Qb + NQ;
  u16* Vb    = Kb + NQ;      // f16
  u16* Vtb   = Vb + NQ;      // f16
  u16* RT    = Vtb + NQ;     // rope table, 8192*16*8 u16 = 2 MB
  u16* Ob    = hsb;          // alias: hs consumed after qkv

  f2bf_kernel<<<8192, 256, 0, stream>>>(hs, hsb, (int)(NQ / 4));
  f2bf_kernel<<<3072, 256, 0, stream>>>(qkvw, qkvwb, 3145728 / 4);
  f2bf_kernel<<<1024, 256, 0, stream>>>(pw, pwb, 1048576 / 4);
  rope_table_kernel<<<512, 256, 0, stream>>>(cs, sn, RT);

  qkv_gemm_kernel<<<dim3(24, 64), 256, 0, stream>>>(hsb, qkvwb, qkvb, RT, Qb, Kb, Vb);
  vtrans_kernel<<<dim3(32, 64), 256, 0, stream>>>(Vb, Vtb);
  attn_kernel<<<dim3(16, 64), 256, 0, stream>>>(Qb, Kb, Vtb, Ob);
  proj_gemm_kernel<<<dim3(8, 64), 256, 0, stream>>>(Ob, pwb, pb, out);
}